// Round 3
// baseline (1521.315 us; speedup 1.0000x reference)
//
#include <hip/hip_runtime.h>
#include <hip/hip_fp16.h>

// ---------------- constants ----------------
namespace {
constexpr int NN = 50000;   // nodes
constexpr int NE = 800000;  // edges
constexpr int NG = 256;     // graphs
constexpr int NF = 34;      // in features
constexpr int NL = 4;       // GAT layers
}
#define EPSB 1e-5f
#define LSLOPE 0.2f
#define INV_SQRT_C 0.17677669529663687f  // 1/sqrt(32)

typedef short bf16x8 __attribute__((ext_vector_type(8)));
typedef float f32x4 __attribute__((ext_vector_type(4)));

static __device__ __forceinline__ short f2bf(float f) {
    unsigned int u = __float_as_uint(f);
    u = (u + 0x7fff + ((u >> 16) & 1)) >> 16;  // RNE
    return (short)u;
}

// ---------------- CSR build ----------------
__global__ void k_deg(const int* __restrict__ ei, int* __restrict__ deg) {
    int e = blockIdx.x * blockDim.x + threadIdx.x;
    if (e < NE) atomicAdd(&deg[ei[NE + e]], 1);
}

__global__ __launch_bounds__(1024) void k_scan(const int* __restrict__ deg, int* __restrict__ rp) {
    __shared__ int sm[1024];
    int t = threadIdx.x;
    const int SEG = (NN + 1023) / 1024;  // 49
    int beg = t * SEG;
    int end = beg + SEG; if (end > NN) end = NN;
    if (beg > NN) beg = NN;
    int s = 0;
    for (int i = beg; i < end; ++i) s += deg[i];
    sm[t] = s;
    __syncthreads();
    for (int off = 1; off < 1024; off <<= 1) {
        int v = (t >= off) ? sm[t - off] : 0;
        __syncthreads();
        sm[t] += v;
        __syncthreads();
    }
    int base = (t == 0) ? 0 : sm[t - 1];
    for (int i = beg; i < end; ++i) { rp[i] = base; base += deg[i]; }
    if (t == 1023) rp[NN] = sm[1023];
}

__global__ void k_fill(const int* __restrict__ ei, int* __restrict__ cursor,
                       int* __restrict__ col, int* __restrict__ dstc) {
    int e = blockIdx.x * blockDim.x + threadIdx.x;
    if (e < NE) {
        int d = ei[NE + e];
        int p = atomicAdd(&cursor[d], 1);
        col[p] = ei[e];
        dstc[p] = d;
    }
}

// ---------------- weight prep: 12x (128,128) fp32 -> transposed bf16 ----------------
__global__ __launch_bounds__(256) void k_prep(const float* __restrict__ gWl,
                                              const float* __restrict__ gWr,
                                              const float* __restrict__ tWq,
                                              const float* __restrict__ tWk,
                                              const float* __restrict__ tWv,
                                              const float* __restrict__ tWs,
                                              short* __restrict__ dst) {
    int m = blockIdx.x;
    const float* src;
    if (m < 4) src = gWl + m * 16384;
    else if (m < 8) src = gWr + (m - 4) * 16384;
    else if (m == 8) src = tWq;
    else if (m == 9) src = tWk;
    else if (m == 10) src = tWv;
    else src = tWs;
    short* d = dst + m * 16384;
    for (int i = threadIdx.x; i < 16384; i += 256) {
        int n = i >> 7, k = i & 127;
        d[i] = f2bf(src[k * 128 + n]);  // Wt[n][k] = W[k][n]
    }
}

// ---------------- MFMA GEMM: (n,128)fp32 @ Wt(bf16,transposed) + bias ----------------
// OUTH=1: store __half, OUTH=0: store float
template <int OUTH>
__global__ __launch_bounds__(256) void k_gemm_mfma(const float* __restrict__ A,
                                                   const short* __restrict__ Wt,
                                                   const float* __restrict__ bias,
                                                   void* __restrict__ outP, int nRows) {
    __shared__ short As[64 * 136];
    __shared__ short Bs[128 * 136];
    int r0 = blockIdx.x * 64;
    int rows = nRows - r0; if (rows > 64) rows = 64;
    const int4* Wt4 = (const int4*)Wt;  // 8 shorts per int4
    for (int idx = threadIdx.x; idx < 2048; idx += 256) {
        int row = idx >> 4, c8 = idx & 15;
        *(int4*)&Bs[row * 136 + c8 * 8] = Wt4[idx];
    }
    for (int idx = threadIdx.x; idx < 2048; idx += 256) {
        int r = idx >> 5, c4 = idx & 31;
        float4 v = make_float4(0.f, 0.f, 0.f, 0.f);
        if (r < rows) v = ((const float4*)A)[(size_t)(r0 + r) * 32 + c4];
        short4 s;
        s.x = f2bf(v.x); s.y = f2bf(v.y); s.z = f2bf(v.z); s.w = f2bf(v.w);
        *(short4*)&As[r * 136 + c4 * 4] = s;
    }
    __syncthreads();
    int lane = threadIdx.x & 63, wave = threadIdx.x >> 6;
    int n16 = lane & 15, quad = lane >> 4;
    int arow = wave * 16 + n16;
    bf16x8 af[4];
#pragma unroll
    for (int kc = 0; kc < 4; ++kc)
        af[kc] = *(const bf16x8*)&As[arow * 136 + kc * 32 + quad * 8];
    f32x4 acc[8];
#pragma unroll
    for (int ct = 0; ct < 8; ++ct) acc[ct] = (f32x4){0.f, 0.f, 0.f, 0.f};
#pragma unroll
    for (int ct = 0; ct < 8; ++ct) {
#pragma unroll
        for (int kc = 0; kc < 4; ++kc) {
            bf16x8 bf = *(const bf16x8*)&Bs[(ct * 16 + n16) * 136 + kc * 32 + quad * 8];
            acc[ct] = __builtin_amdgcn_mfma_f32_16x16x32_bf16(af[kc], bf, acc[ct], 0, 0, 0);
        }
    }
#pragma unroll
    for (int ct = 0; ct < 8; ++ct) {
        int col = ct * 16 + n16;
        float b = bias[col];
#pragma unroll
        for (int reg = 0; reg < 4; ++reg) {
            int r = wave * 16 + quad * 4 + reg;  // C/D: col=lane&15, row=quad*4+reg
            if (r < rows) {
                float v = acc[ct][reg] + b;
                if (OUTH)
                    ((__half*)outP)[(size_t)(r0 + r) * 128 + col] = __float2half(v);
                else
                    ((float*)outP)[(size_t)(r0 + r) * 128 + col] = v;
            }
        }
    }
}

// ---------------- GEMM: (n,34) @ (34,128) + bias (fp32 VALU) ----------
__global__ __launch_bounds__(256) void k_gemm_emb(const float* __restrict__ A,
                                                  const float* __restrict__ W,
                                                  const float* __restrict__ bias,
                                                  float* __restrict__ out, int nRows) {
    __shared__ float As[64 * NF];
    int r0 = blockIdx.x * 64;
    int rows = nRows - r0; if (rows > 64) rows = 64;
    int total = rows * NF;
    for (int idx = threadIdx.x; idx < 64 * NF; idx += 256)
        As[idx] = (idx < total) ? A[(size_t)r0 * NF + idx] : 0.f;
    __syncthreads();
    int tx = threadIdx.x & 31, ty = threadIdx.x >> 5;
    const float4* W4 = (const float4*)W;
    float acc[8][4];
#pragma unroll
    for (int j = 0; j < 8; ++j)
#pragma unroll
        for (int i = 0; i < 4; ++i) acc[j][i] = 0.f;
#pragma unroll 2
    for (int k = 0; k < NF; ++k) {
        float4 w = W4[k * 32 + tx];
#pragma unroll
        for (int j = 0; j < 8; ++j) {
            float a = As[(ty * 8 + j) * NF + k];
            acc[j][0] += a * w.x; acc[j][1] += a * w.y;
            acc[j][2] += a * w.z; acc[j][3] += a * w.w;
        }
    }
    float4 b = ((const float4*)bias)[tx];
#pragma unroll
    for (int j = 0; j < 8; ++j) {
        int r = ty * 8 + j;
        if (r < rows) {
            float4 o = make_float4(acc[j][0] + b.x, acc[j][1] + b.y,
                                   acc[j][2] + b.z, acc[j][3] + b.w);
            ((float4*)out)[(size_t)(r0 + r) * 32 + tx] = o;
        }
    }
}

// ---------------- BN statistics (per-column sum / sumsq) ----------------
__global__ __launch_bounds__(256) void k_stats(const float* __restrict__ src, int nRows,
                                               float* __restrict__ st) {
    int c = threadIdx.x & 127;
    int sub = threadIdx.x >> 7;  // 0/1
    int r0 = blockIdx.x * 128;
    int rend = r0 + 128; if (rend > nRows) rend = nRows;
    float s = 0.f, ss = 0.f;
    for (int r = r0 + sub; r < rend; r += 2) {
        float v = src[(size_t)r * 128 + c];
        s += v; ss += v * v;
    }
    atomicAdd(&st[c], s);
    atomicAdd(&st[128 + c], ss);
}

// dst = (doRes ? dst : 0) + maybe_relu(bn(src))  -- finalize folded in
__global__ __launch_bounds__(256) void k_bn_apply(float* __restrict__ dst,
                                                  const float* __restrict__ src,
                                                  const float* __restrict__ st,
                                                  const float* __restrict__ g,
                                                  const float* __restrict__ b,
                                                  float invn, int doRelu, int doRes) {
    int tid = blockIdx.x * blockDim.x + threadIdx.x;
    int cb = (tid & 31) * 4;  // grid-stride is a multiple of 32 -> cb invariant
    float sc[4], sh[4];
#pragma unroll
    for (int k = 0; k < 4; ++k) {
        float mean = st[cb + k] * invn;
        float var = fmaxf(st[128 + cb + k] * invn - mean * mean, 0.f);
        float s = g[cb + k] * rsqrtf(var + EPSB);
        sc[k] = s; sh[k] = b[cb + k] - mean * s;
    }
    const float4* s4 = (const float4*)src;
    float4* d4 = (float4*)dst;
    const int total = NN * 32;
    for (int i = tid; i < total; i += gridDim.x * blockDim.x) {
        float4 v = s4[i];
        v.x = v.x * sc[0] + sh[0]; v.y = v.y * sc[1] + sh[1];
        v.z = v.z * sc[2] + sh[2]; v.w = v.w * sc[3] + sh[3];
        if (doRelu) {
            v.x = fmaxf(v.x, 0.f); v.y = fmaxf(v.y, 0.f);
            v.z = fmaxf(v.z, 0.f); v.w = fmaxf(v.w, 0.f);
        }
        if (doRes) {
            float4 o = d4[i];
            v.x += o.x; v.y += o.y; v.z += o.z; v.w += o.w;
        }
        d4[i] = v;
    }
}

// ---------------- GAT score: one thread per (CSR slot, head) ----------------
// slots [0,NE) are real edges; slots [NE,NE+NN) are self-loops.
__global__ __launch_bounds__(256) void k_gat_score(const __half* __restrict__ xl,
                                                   const __half* __restrict__ xr,
                                                   const float* __restrict__ att,
                                                   const int* __restrict__ col,
                                                   const int* __restrict__ dstc,
                                                   float* __restrict__ sc) {
    __shared__ float attS[128];
    if (threadIdx.x < 128) attS[threadIdx.x] = att[threadIdx.x];
    __syncthreads();
    int idx = blockIdx.x * 256 + threadIdx.x;
    int slot = idx >> 2, head = idx & 3;
    if (slot >= NE + NN) return;
    int s, d;
    if (slot < NE) { s = col[slot]; d = dstc[slot]; }
    else { s = slot - NE; d = s; }
    const __half2* xl2 = (const __half2*)xl + (size_t)s * 64 + head * 16;
    const __half2* xr2 = (const __half2*)xr + (size_t)d * 64 + head * 16;
    float acc = 0.f;
#pragma unroll
    for (int j = 0; j < 16; ++j) {
        float2 a = __half22float2(xl2[j]);
        float2 b = __half22float2(xr2[j]);
        float ex = a.x + b.x, ey = a.y + b.y;
        ex = fmaxf(ex, 0.f) + LSLOPE * fminf(ex, 0.f);
        ey = fmaxf(ey, 0.f) + LSLOPE * fminf(ey, 0.f);
        acc += ex * attS[head * 32 + 2 * j] + ey * attS[head * 32 + 2 * j + 1];
    }
    // scores are bounded (|acc| << 80): exp without max-shift is exact math
    sc[idx] = __expf(acc);
}

// ---------------- Transformer score: one thread per (slot, head) ----------------
__global__ __launch_bounds__(256) void k_trans_score(const __half* __restrict__ qh,
                                                     const __half* __restrict__ kh,
                                                     const int* __restrict__ col,
                                                     const int* __restrict__ dstc,
                                                     float* __restrict__ sc) {
    int idx = blockIdx.x * 256 + threadIdx.x;
    int slot = idx >> 2, head = idx & 3;
    if (slot >= NE) return;
    int s = col[slot], d = dstc[slot];
    const __half2* q2 = (const __half2*)qh + (size_t)d * 64 + head * 16;
    const __half2* k2 = (const __half2*)kh + (size_t)s * 64 + head * 16;
    float acc = 0.f;
#pragma unroll
    for (int j = 0; j < 16; ++j) {
        float2 a = __half22float2(q2[j]);
        float2 b = __half22float2(k2[j]);
        acc += a.x * b.x + a.y * b.y;
    }
    sc[idx] = __expf(acc * INV_SQRT_C);
}

// ---------------- GAT aggregate: wave per node, no shfl, no exp ----------------
__global__ __launch_bounds__(256) void k_gat_aggr(const __half* __restrict__ xl,
                                                  const float* __restrict__ sc,
                                                  const float* __restrict__ gbias_l,
                                                  const int* __restrict__ rp,
                                                  const int* __restrict__ col,
                                                  float* __restrict__ out) {
    int lane = threadIdx.x & 63;
    int node = blockIdx.x * 4 + (threadIdx.x >> 6);
    if (node >= NN) return;
    int head = lane >> 4;
    const __half2* xl2 = (const __half2*)xl;
    float ax = 0.f, ay = 0.f, l = 0.f;
    int s0 = rp[node], s1 = rp[node + 1];
    for (int slot = s0; slot < s1; ++slot) {
        float w = sc[slot * 4 + head];
        float2 f = __half22float2(xl2[(size_t)col[slot] * 64 + lane]);
        ax += w * f.x; ay += w * f.y; l += w;
    }
    {   // self loop
        float w = sc[(size_t)(NE + node) * 4 + head];
        float2 f = __half22float2(xl2[(size_t)node * 64 + lane]);
        ax += w * f.x; ay += w * f.y; l += w;
    }
    float inv = 1.f / (l + 1e-16f);
    int c = lane * 2;
    float2 gb = *(const float2*)&gbias_l[c];
    *(float2*)&out[(size_t)node * 128 + c] = make_float2(ax * inv + gb.x, ay * inv + gb.y);
}

// ---------------- Transformer aggregate (no self loops, + skip) ----------------
__global__ __launch_bounds__(256) void k_trans_aggr(const __half* __restrict__ vv,
                                                    const float* __restrict__ sc,
                                                    const float* __restrict__ sT,
                                                    const int* __restrict__ rp,
                                                    const int* __restrict__ col,
                                                    float* __restrict__ out) {
    int lane = threadIdx.x & 63;
    int node = blockIdx.x * 4 + (threadIdx.x >> 6);
    if (node >= NN) return;
    int head = lane >> 4;
    const __half2* v2p = (const __half2*)vv;
    float ax = 0.f, ay = 0.f, l = 0.f;
    int s0 = rp[node], s1 = rp[node + 1];
    for (int slot = s0; slot < s1; ++slot) {
        float w = sc[slot * 4 + head];
        float2 f = __half22float2(v2p[(size_t)col[slot] * 64 + lane]);
        ax += w * f.x; ay += w * f.y; l += w;
    }
    float inv = 1.f / (l + 1e-16f);
    int c = lane * 2;
    float2 st2 = *(const float2*)&sT[(size_t)node * 128 + c];
    *(float2*)&out[(size_t)node * 128 + c] = make_float2(ax * inv + st2.x, ay * inv + st2.y);
}

// ---------------- pooling: per-graph mean + max (batch sorted) ----------------
__global__ __launch_bounds__(128) void k_pool(const float* __restrict__ x,
                                              const int* __restrict__ batch,
                                              float* __restrict__ h) {
    int g = blockIdx.x;
    int lo = 0, hi = NN;
    while (lo < hi) { int mid = (lo + hi) >> 1; if (batch[mid] < g) lo = mid + 1; else hi = mid; }
    int start = lo;
    hi = NN;
    while (lo < hi) { int mid = (lo + hi) >> 1; if (batch[mid] < g + 1) lo = mid + 1; else hi = mid; }
    int end = lo;
    int c = threadIdx.x;
    float s = 0.f, mx = -INFINITY;
    for (int r = start; r < end; ++r) {
        float v = x[(size_t)r * 128 + c];
        s += v; mx = fmaxf(mx, v);
    }
    int cnt = end - start;
    float xm = s / fmaxf((float)cnt, 1.f);
    float xx = (cnt > 0) ? mx : 0.f;
    h[g * 256 + c] = xm;
    h[g * 256 + 128 + c] = xx;
}

// ---------------- head ----------------
__global__ __launch_bounds__(128) void k_head1(const float* __restrict__ h,
                                               const float* __restrict__ W,
                                               const float* __restrict__ b,
                                               float* __restrict__ t1) {
    __shared__ float hr[256];
    int row = blockIdx.x;
    int t = threadIdx.x;
    hr[t] = h[row * 256 + t];
    hr[t + 128] = h[row * 256 + 128 + t];
    __syncthreads();
    float acc = b[t];
#pragma unroll 4
    for (int k = 0; k < 256; ++k) acc += hr[k] * W[k * 128 + t];
    t1[row * 128 + t] = acc;
}

__global__ __launch_bounds__(64) void k_head2(const float* __restrict__ t1,
                                              const float* __restrict__ st,
                                              const float* __restrict__ og,
                                              const float* __restrict__ obe,
                                              const float* __restrict__ W2,
                                              const float* __restrict__ b2,
                                              const float* __restrict__ W3,
                                              const float* __restrict__ b3,
                                              float* __restrict__ out) {
    __shared__ float v[128];
    int row = blockIdx.x, t = threadIdx.x;
    const float invn = 1.f / NG;
#pragma unroll
    for (int half = 0; half < 2; ++half) {
        int ch = t + half * 64;
        float mean = st[ch] * invn;
        float var = fmaxf(st[128 + ch] * invn - mean * mean, 0.f);
        float scv = og[ch] * rsqrtf(var + EPSB);
        float shv = obe[ch] - mean * scv;
        float a = t1[row * 128 + ch] * scv + shv;
        v[ch] = fmaxf(a, 0.f);
    }
    __syncthreads();
    float acc = b2[t];
#pragma unroll 4
    for (int k = 0; k < 128; ++k) acc += v[k] * W2[k * 64 + t];
    float p = fmaxf(acc, 0.f) * W3[t];
    p += __shfl_xor(p, 1); p += __shfl_xor(p, 2); p += __shfl_xor(p, 4);
    p += __shfl_xor(p, 8); p += __shfl_xor(p, 16); p += __shfl_xor(p, 32);
    if (t == 0) out[row] = p + b3[0];
}

// ---------------- launch ----------------
extern "C" void kernel_launch(void* const* d_in, const int* in_sizes, int n_in,
                              void* d_out, int out_size, void* d_ws, size_t ws_size,
                              hipStream_t stream) {
    const float* x_in   = (const float*)d_in[0];
    const int*   ei     = (const int*)d_in[1];
    const int*   batch  = (const int*)d_in[2];
    const float* emb_W  = (const float*)d_in[3];
    const float* emb_b  = (const float*)d_in[4];
    const float* emb_g  = (const float*)d_in[5];
    const float* emb_be = (const float*)d_in[6];
    const float* gWl    = (const float*)d_in[7];
    const float* gWr    = (const float*)d_in[8];
    const float* gbl    = (const float*)d_in[9];
    const float* gbr    = (const float*)d_in[10];
    const float* gatt   = (const float*)d_in[11];
    const float* gbias  = (const float*)d_in[12];
    const float* gg     = (const float*)d_in[13];
    const float* gbe    = (const float*)d_in[14];
    const float* tWq    = (const float*)d_in[15];
    const float* tWk    = (const float*)d_in[16];
    const float* tWv    = (const float*)d_in[17];
    const float* tWs    = (const float*)d_in[18];
    const float* tbq    = (const float*)d_in[19];
    const float* tbk    = (const float*)d_in[20];
    const float* tbv    = (const float*)d_in[21];
    const float* tbs    = (const float*)d_in[22];
    const float* tg     = (const float*)d_in[23];
    const float* tbe    = (const float*)d_in[24];
    const float* oW1    = (const float*)d_in[25];
    const float* ob1    = (const float*)d_in[26];
    const float* og     = (const float*)d_in[27];
    const float* obe    = (const float*)d_in[28];
    const float* oW2    = (const float*)d_in[29];
    const float* ob2    = (const float*)d_in[30];
    const float* oW3    = (const float*)d_in[31];
    const float* ob3    = (const float*)d_in[32];
    float* out = (float*)d_out;

    const size_t NDsz = (size_t)NN * 128;
    float* x     = (float*)d_ws;
    float* bA    = x + NDsz;
    float* bC    = bA + NDsz;
    float* stats = bC + NDsz;        // 7 * 256 floats
    float* hpool = stats + 7 * 256;  // 256*256
    float* t1    = hpool + 65536;    // 256*128
    float* scb   = t1 + 32768;                 // (NE+NN)*4 scores
    __half* xlh  = (__half*)(scb + (size_t)(NE + NN) * 4);  // xl / K
    __half* xrh  = xlh + NDsz;                 // xr / Q
    __half* vh   = xrh + NDsz;                 // V
    short* Wt    = (short*)(vh + NDsz);        // 12 * 128*128 bf16 transposed
    int* deg     = (int*)(Wt + 12 * 16384);
    int* rp      = deg + NN;
    int* cursor  = rp + NN + 1;
    int* colb    = cursor + NN;
    int* dstc    = colb + NE;

    hipMemsetAsync(deg, 0, NN * sizeof(int), stream);
    hipMemsetAsync(stats, 0, 7 * 256 * sizeof(float), stream);

    // weight prep (bf16 transposed)
    k_prep<<<12, 256, 0, stream>>>(gWl, gWr, tWq, tWk, tWv, tWs, Wt);

    // CSR by destination
    k_deg<<<(NE + 255) / 256, 256, 0, stream>>>(ei, deg);
    k_scan<<<1, 1024, 0, stream>>>(deg, rp);
    hipMemcpyAsync(cursor, rp, NN * sizeof(int), hipMemcpyDeviceToDevice, stream);
    k_fill<<<(NE + 255) / 256, 256, 0, stream>>>(ei, cursor, colb, dstc);

    const int gGemm = (NN + 63) / 64;
    const int gStat = (NN + 127) / 128;
    const int gNode = (NN + 3) / 4;
    const int gScG  = ((NE + NN) * 4 + 255) / 256;
    const int gScT  = (NE * 4 + 255) / 256;

    // embedding + BN + relu
    k_gemm_emb<<<gGemm, 256, 0, stream>>>(x_in, emb_W, emb_b, bA, NN);
    k_stats<<<gStat, 256, 0, stream>>>(bA, NN, stats);
    k_bn_apply<<<1024, 256, 0, stream>>>(x, bA, stats, emb_g, emb_be, 1.f / NN, 1, 0);

    // 4 GATv2 layers
    for (int l = 0; l < NL; ++l) {
        k_gemm_mfma<1><<<gGemm, 256, 0, stream>>>(x, Wt + (size_t)l * 16384, gbl + l * 128, xlh, NN);
        k_gemm_mfma<1><<<gGemm, 256, 0, stream>>>(x, Wt + (size_t)(4 + l) * 16384, gbr + l * 128, xrh, NN);
        k_gat_score<<<gScG, 256, 0, stream>>>(xlh, xrh, gatt + l * 128, colb, dstc, scb);
        k_gat_aggr<<<gNode, 256, 0, stream>>>(xlh, scb, gbias + l * 128, rp, colb, bC);
        k_stats<<<gStat, 256, 0, stream>>>(bC, NN, stats + (1 + l) * 256);
        k_bn_apply<<<1024, 256, 0, stream>>>(x, bC, stats + (1 + l) * 256, gg + l * 128, gbe + l * 128, 1.f / NN, 1, 1);
    }

    // TransformerConv
    k_gemm_mfma<1><<<gGemm, 256, 0, stream>>>(x, Wt + (size_t)8 * 16384, tbq, xrh, NN);   // Q
    k_gemm_mfma<1><<<gGemm, 256, 0, stream>>>(x, Wt + (size_t)9 * 16384, tbk, xlh, NN);   // K
    k_gemm_mfma<1><<<gGemm, 256, 0, stream>>>(x, Wt + (size_t)10 * 16384, tbv, vh, NN);   // V
    k_gemm_mfma<0><<<gGemm, 256, 0, stream>>>(x, Wt + (size_t)11 * 16384, tbs, bA, NN);   // skip (fp32)
    k_trans_score<<<gScT, 256, 0, stream>>>(xrh, xlh, colb, dstc, scb);
    k_trans_aggr<<<gNode, 256, 0, stream>>>(vh, scb, bA, rp, colb, bC);
    k_stats<<<gStat, 256, 0, stream>>>(bC, NN, stats + 5 * 256);
    k_bn_apply<<<1024, 256, 0, stream>>>(x, bC, stats + 5 * 256, tg, tbe, 1.f / NN, 0, 1);

    // pooling + head
    k_pool<<<NG, 128, 0, stream>>>(x, batch, hpool);
    k_head1<<<NG, 128, 0, stream>>>(hpool, oW1, ob1, t1);
    k_stats<<<(NG + 127) / 128, 256, 0, stream>>>(t1, NG, stats + 6 * 256);
    k_head2<<<NG, 64, 0, stream>>>(t1, stats + 6 * 256, og, obe, oW2, ob2, oW3, ob3, out);
}

// Round 4
// 1271.698 us; speedup vs baseline: 1.1963x; 1.1963x over previous
//
#include <hip/hip_runtime.h>
#include <hip/hip_fp16.h>

// ---------------- constants ----------------
namespace {
constexpr int NN = 50000;   // nodes
constexpr int NE = 800000;  // edges
constexpr int NG = 256;     // graphs
constexpr int NF = 34;      // in features
constexpr int NL = 4;       // GAT layers
}
#define EPSB 1e-5f
#define LSLOPE 0.2f
#define INV_SQRT_C 0.17677669529663687f  // 1/sqrt(32)

typedef short bf16x8 __attribute__((ext_vector_type(8)));
typedef float f32x4 __attribute__((ext_vector_type(4)));

static __device__ __forceinline__ short f2bf(float f) {
    unsigned int u = __float_as_uint(f);
    u = (u + 0x7fff + ((u >> 16) & 1)) >> 16;  // RNE
    return (short)u;
}

// ---------------- CSR build ----------------
__global__ void k_deg(const int* __restrict__ ei, int* __restrict__ deg) {
    int e = blockIdx.x * blockDim.x + threadIdx.x;
    if (e < NE) atomicAdd(&deg[ei[NE + e]], 1);
}

__global__ __launch_bounds__(1024) void k_scan(const int* __restrict__ deg, int* __restrict__ rp) {
    __shared__ int sm[1024];
    int t = threadIdx.x;
    const int SEG = (NN + 1023) / 1024;  // 49
    int beg = t * SEG;
    int end = beg + SEG; if (end > NN) end = NN;
    if (beg > NN) beg = NN;
    int s = 0;
    for (int i = beg; i < end; ++i) s += deg[i];
    sm[t] = s;
    __syncthreads();
    for (int off = 1; off < 1024; off <<= 1) {
        int v = (t >= off) ? sm[t - off] : 0;
        __syncthreads();
        sm[t] += v;
        __syncthreads();
    }
    int base = (t == 0) ? 0 : sm[t - 1];
    for (int i = beg; i < end; ++i) { rp[i] = base; base += deg[i]; }
    if (t == 1023) rp[NN] = sm[1023];
}

__global__ void k_fill(const int* __restrict__ ei, int* __restrict__ cursor,
                       int* __restrict__ col, int* __restrict__ dstc) {
    int e = blockIdx.x * blockDim.x + threadIdx.x;
    if (e < NE) {
        int d = ei[NE + e];
        int p = atomicAdd(&cursor[d], 1);
        col[p] = ei[e];
        dstc[p] = d;
    }
}

// ---------------- weight prep: 12x (128,128) fp32 -> transposed bf16 ----------------
__global__ __launch_bounds__(256) void k_prep(const float* __restrict__ gWl,
                                              const float* __restrict__ gWr,
                                              const float* __restrict__ tWq,
                                              const float* __restrict__ tWk,
                                              const float* __restrict__ tWv,
                                              const float* __restrict__ tWs,
                                              short* __restrict__ dst) {
    int m = blockIdx.x;
    const float* src;
    if (m < 4) src = gWl + m * 16384;
    else if (m < 8) src = gWr + (m - 4) * 16384;
    else if (m == 8) src = tWq;
    else if (m == 9) src = tWk;
    else if (m == 10) src = tWv;
    else src = tWs;
    short* d = dst + m * 16384;
    for (int i = threadIdx.x; i < 16384; i += 256) {
        int n = i >> 7, k = i & 127;
        d[i] = f2bf(src[k * 128 + n]);  // Wt[n][k] = W[k][n]
    }
}

// ---------------- pair-fused MFMA GEMM: A(n,128)fp32 @ {Wt0,Wt1} + bias ----------------
// A staged to LDS once (fp32->bf16); B staged twice sequentially.
template <int OUTH0, int OUTH1>
__global__ __launch_bounds__(256) void k_gemm2(const float* __restrict__ A,
                                               const short* __restrict__ Wt0,
                                               const short* __restrict__ Wt1,
                                               const float* __restrict__ bias0,
                                               const float* __restrict__ bias1,
                                               void* __restrict__ out0,
                                               void* __restrict__ out1, int nRows) {
    __shared__ short As[64 * 136];
    __shared__ short Bs[128 * 136];
    int r0 = blockIdx.x * 64;
    int rows = nRows - r0; if (rows > 64) rows = 64;
    // stage A (fp32 -> bf16)
    for (int idx = threadIdx.x; idx < 2048; idx += 256) {
        int r = idx >> 5, c4 = idx & 31;
        float4 v = make_float4(0.f, 0.f, 0.f, 0.f);
        if (r < rows) v = ((const float4*)A)[(size_t)(r0 + r) * 32 + c4];
        short4 s;
        s.x = f2bf(v.x); s.y = f2bf(v.y); s.z = f2bf(v.z); s.w = f2bf(v.w);
        *(short4*)&As[r * 136 + c4 * 4] = s;
    }
    // stage B0
    {
        const int4* Wt4 = (const int4*)Wt0;
        for (int idx = threadIdx.x; idx < 2048; idx += 256) {
            int row = idx >> 4, c8 = idx & 15;
            *(int4*)&Bs[row * 136 + c8 * 8] = Wt4[idx];
        }
    }
    __syncthreads();
    int lane = threadIdx.x & 63, wave = threadIdx.x >> 6;
    int n16 = lane & 15, quad = lane >> 4;
    int arow = wave * 16 + n16;
    bf16x8 af[4];
#pragma unroll
    for (int kc = 0; kc < 4; ++kc)
        af[kc] = *(const bf16x8*)&As[arow * 136 + kc * 32 + quad * 8];

    // ---- matrix 0 ----
    f32x4 acc[8];
#pragma unroll
    for (int ct = 0; ct < 8; ++ct) acc[ct] = (f32x4){0.f, 0.f, 0.f, 0.f};
#pragma unroll
    for (int ct = 0; ct < 8; ++ct)
#pragma unroll
        for (int kc = 0; kc < 4; ++kc) {
            bf16x8 bf = *(const bf16x8*)&Bs[(ct * 16 + n16) * 136 + kc * 32 + quad * 8];
            acc[ct] = __builtin_amdgcn_mfma_f32_16x16x32_bf16(af[kc], bf, acc[ct], 0, 0, 0);
        }
#pragma unroll
    for (int ct = 0; ct < 8; ++ct) {
        int colI = ct * 16 + n16;
        float b = bias0[colI];
#pragma unroll
        for (int reg = 0; reg < 4; ++reg) {
            int r = wave * 16 + quad * 4 + reg;  // C/D: col=lane&15, row=quad*4+reg
            if (r < rows) {
                float v = acc[ct][reg] + b;
                if (OUTH0) ((__half*)out0)[(size_t)(r0 + r) * 128 + colI] = __float2half(v);
                else       ((float*)out0)[(size_t)(r0 + r) * 128 + colI] = v;
            }
        }
    }
    __syncthreads();
    // stage B1
    {
        const int4* Wt4 = (const int4*)Wt1;
        for (int idx = threadIdx.x; idx < 2048; idx += 256) {
            int row = idx >> 4, c8 = idx & 15;
            *(int4*)&Bs[row * 136 + c8 * 8] = Wt4[idx];
        }
    }
    __syncthreads();
    // ---- matrix 1 ----
#pragma unroll
    for (int ct = 0; ct < 8; ++ct) acc[ct] = (f32x4){0.f, 0.f, 0.f, 0.f};
#pragma unroll
    for (int ct = 0; ct < 8; ++ct)
#pragma unroll
        for (int kc = 0; kc < 4; ++kc) {
            bf16x8 bf = *(const bf16x8*)&Bs[(ct * 16 + n16) * 136 + kc * 32 + quad * 8];
            acc[ct] = __builtin_amdgcn_mfma_f32_16x16x32_bf16(af[kc], bf, acc[ct], 0, 0, 0);
        }
#pragma unroll
    for (int ct = 0; ct < 8; ++ct) {
        int colI = ct * 16 + n16;
        float b = bias1[colI];
#pragma unroll
        for (int reg = 0; reg < 4; ++reg) {
            int r = wave * 16 + quad * 4 + reg;
            if (r < rows) {
                float v = acc[ct][reg] + b;
                if (OUTH1) ((__half*)out1)[(size_t)(r0 + r) * 128 + colI] = __float2half(v);
                else       ((float*)out1)[(size_t)(r0 + r) * 128 + colI] = v;
            }
        }
    }
}

// ---------------- GEMM: (n,34) @ (34,128) + bias (fp32 VALU) ----------
__global__ __launch_bounds__(256) void k_gemm_emb(const float* __restrict__ A,
                                                  const float* __restrict__ W,
                                                  const float* __restrict__ bias,
                                                  float* __restrict__ out, int nRows) {
    __shared__ float As[64 * NF];
    int r0 = blockIdx.x * 64;
    int rows = nRows - r0; if (rows > 64) rows = 64;
    int total = rows * NF;
    for (int idx = threadIdx.x; idx < 64 * NF; idx += 256)
        As[idx] = (idx < total) ? A[(size_t)r0 * NF + idx] : 0.f;
    __syncthreads();
    int tx = threadIdx.x & 31, ty = threadIdx.x >> 5;
    const float4* W4 = (const float4*)W;
    float acc[8][4];
#pragma unroll
    for (int j = 0; j < 8; ++j)
#pragma unroll
        for (int i = 0; i < 4; ++i) acc[j][i] = 0.f;
#pragma unroll 2
    for (int k = 0; k < NF; ++k) {
        float4 w = W4[k * 32 + tx];
#pragma unroll
        for (int j = 0; j < 8; ++j) {
            float a = As[(ty * 8 + j) * NF + k];
            acc[j][0] += a * w.x; acc[j][1] += a * w.y;
            acc[j][2] += a * w.z; acc[j][3] += a * w.w;
        }
    }
    float4 b = ((const float4*)bias)[tx];
#pragma unroll
    for (int j = 0; j < 8; ++j) {
        int r = ty * 8 + j;
        if (r < rows) {
            float4 o = make_float4(acc[j][0] + b.x, acc[j][1] + b.y,
                                   acc[j][2] + b.z, acc[j][3] + b.w);
            ((float4*)out)[(size_t)(r0 + r) * 32 + tx] = o;
        }
    }
}

// ---------------- BN statistics (per-column sum / sumsq) ----------------
__global__ __launch_bounds__(256) void k_stats(const float* __restrict__ src, int nRows,
                                               float* __restrict__ st) {
    int c = threadIdx.x & 127;
    int sub = threadIdx.x >> 7;  // 0/1
    int r0 = blockIdx.x * 128;
    int rend = r0 + 128; if (rend > nRows) rend = nRows;
    float s = 0.f, ss = 0.f;
    for (int r = r0 + sub; r < rend; r += 2) {
        float v = src[(size_t)r * 128 + c];
        s += v; ss += v * v;
    }
    atomicAdd(&st[c], s);
    atomicAdd(&st[128 + c], ss);
}

// dst = (doRes ? dst : 0) + maybe_relu(bn(src))  -- finalize folded in
__global__ __launch_bounds__(256) void k_bn_apply(float* __restrict__ dst,
                                                  const float* __restrict__ src,
                                                  const float* __restrict__ st,
                                                  const float* __restrict__ g,
                                                  const float* __restrict__ b,
                                                  float invn, int doRelu, int doRes) {
    int tid = blockIdx.x * blockDim.x + threadIdx.x;
    int cb = (tid & 31) * 4;  // grid-stride is a multiple of 32 -> cb invariant
    float sc[4], sh[4];
#pragma unroll
    for (int k = 0; k < 4; ++k) {
        float mean = st[cb + k] * invn;
        float var = fmaxf(st[128 + cb + k] * invn - mean * mean, 0.f);
        float s = g[cb + k] * rsqrtf(var + EPSB);
        sc[k] = s; sh[k] = b[cb + k] - mean * s;
    }
    const float4* s4 = (const float4*)src;
    float4* d4 = (float4*)dst;
    const int total = NN * 32;
    for (int i = tid; i < total; i += gridDim.x * blockDim.x) {
        float4 v = s4[i];
        v.x = v.x * sc[0] + sh[0]; v.y = v.y * sc[1] + sh[1];
        v.z = v.z * sc[2] + sh[2]; v.w = v.w * sc[3] + sh[3];
        if (doRelu) {
            v.x = fmaxf(v.x, 0.f); v.y = fmaxf(v.y, 0.f);
            v.z = fmaxf(v.z, 0.f); v.w = fmaxf(v.w, 0.f);
        }
        if (doRes) {
            float4 o = d4[i];
            v.x += o.x; v.y += o.y; v.z += o.z; v.w += o.w;
        }
        d4[i] = v;
    }
}

// ---------------- GAT score: one thread per (CSR slot, head) ----------------
__global__ __launch_bounds__(256) void k_gat_score(const __half* __restrict__ xl,
                                                   const __half* __restrict__ xr,
                                                   const float* __restrict__ att,
                                                   const int* __restrict__ col,
                                                   const int* __restrict__ dstc,
                                                   float* __restrict__ sc) {
    __shared__ float attS[128];
    if (threadIdx.x < 128) attS[threadIdx.x] = att[threadIdx.x];
    __syncthreads();
    int idx = blockIdx.x * 256 + threadIdx.x;
    int slot = idx >> 2, head = idx & 3;
    if (slot >= NE + NN) return;
    int s, d;
    if (slot < NE) { s = col[slot]; d = dstc[slot]; }
    else { s = slot - NE; d = s; }
    const __half2* xl2 = (const __half2*)xl + (size_t)s * 64 + head * 16;
    const __half2* xr2 = (const __half2*)xr + (size_t)d * 64 + head * 16;
    float acc = 0.f;
#pragma unroll
    for (int j = 0; j < 16; ++j) {
        float2 a = __half22float2(xl2[j]);
        float2 b = __half22float2(xr2[j]);
        float ex = a.x + b.x, ey = a.y + b.y;
        ex = fmaxf(ex, 0.f) + LSLOPE * fminf(ex, 0.f);
        ey = fmaxf(ey, 0.f) + LSLOPE * fminf(ey, 0.f);
        acc += ex * attS[head * 32 + 2 * j] + ey * attS[head * 32 + 2 * j + 1];
    }
    sc[idx] = __expf(acc);  // scores bounded; shift-free exp is exact math
}

// ---------------- Transformer score: one thread per (slot, head) ----------------
__global__ __launch_bounds__(256) void k_trans_score(const __half* __restrict__ qh,
                                                     const __half* __restrict__ kh,
                                                     const int* __restrict__ col,
                                                     const int* __restrict__ dstc,
                                                     float* __restrict__ sc) {
    int idx = blockIdx.x * 256 + threadIdx.x;
    int slot = idx >> 2, head = idx & 3;
    if (slot >= NE) return;
    int s = col[slot], d = dstc[slot];
    const __half2* q2 = (const __half2*)qh + (size_t)d * 64 + head * 16;
    const __half2* k2 = (const __half2*)kh + (size_t)s * 64 + head * 16;
    float acc = 0.f;
#pragma unroll
    for (int j = 0; j < 16; ++j) {
        float2 a = __half22float2(q2[j]);
        float2 b = __half22float2(k2[j]);
        acc += a.x * b.x + a.y * b.y;
    }
    sc[idx] = __expf(acc * INV_SQRT_C);
}

// ---------------- GAT aggregate: wave/node, unroll-4 batched gathers ----------------
__global__ __launch_bounds__(256) void k_gat_aggr(const __half* __restrict__ xl,
                                                  const float* __restrict__ sc,
                                                  const float* __restrict__ gbias_l,
                                                  const int* __restrict__ rp,
                                                  const int* __restrict__ col,
                                                  float* __restrict__ out) {
    int lane = threadIdx.x & 63;
    int node = blockIdx.x * 4 + (threadIdx.x >> 6);
    if (node >= NN) return;
    int head = lane >> 4;
    const __half2* xl2 = (const __half2*)xl;
    float ax = 0.f, ay = 0.f, l = 0.f;
    int s0 = rp[node], s1 = rp[node + 1];
    int n = s1 - s0;
    int i = 0;
    for (; i + 4 <= n; i += 4) {
        int base = s0 + i;
        int c0 = col[base], c1 = col[base + 1], c2 = col[base + 2], c3 = col[base + 3];
        float w0 = sc[(size_t)base * 4 + head];
        float w1 = sc[(size_t)(base + 1) * 4 + head];
        float w2 = sc[(size_t)(base + 2) * 4 + head];
        float w3 = sc[(size_t)(base + 3) * 4 + head];
        float2 f0 = __half22float2(xl2[(size_t)c0 * 64 + lane]);
        float2 f1 = __half22float2(xl2[(size_t)c1 * 64 + lane]);
        float2 f2 = __half22float2(xl2[(size_t)c2 * 64 + lane]);
        float2 f3 = __half22float2(xl2[(size_t)c3 * 64 + lane]);
        ax += w0 * f0.x; ay += w0 * f0.y;
        ax += w1 * f1.x; ay += w1 * f1.y;
        ax += w2 * f2.x; ay += w2 * f2.y;
        ax += w3 * f3.x; ay += w3 * f3.y;
        l += w0 + w1 + w2 + w3;
    }
    for (; i < n; ++i) {
        int slot = s0 + i;
        float w = sc[(size_t)slot * 4 + head];
        float2 f = __half22float2(xl2[(size_t)col[slot] * 64 + lane]);
        ax += w * f.x; ay += w * f.y; l += w;
    }
    {   // self loop
        float w = sc[(size_t)(NE + node) * 4 + head];
        float2 f = __half22float2(xl2[(size_t)node * 64 + lane]);
        ax += w * f.x; ay += w * f.y; l += w;
    }
    float inv = 1.f / (l + 1e-16f);
    int c = lane * 2;
    float2 gb = *(const float2*)&gbias_l[c];
    *(float2*)&out[(size_t)node * 128 + c] = make_float2(ax * inv + gb.x, ay * inv + gb.y);
}

// ---------------- Transformer aggregate (no self loops, + skip) ----------------
__global__ __launch_bounds__(256) void k_trans_aggr(const __half* __restrict__ vv,
                                                    const float* __restrict__ sc,
                                                    const float* __restrict__ sT,
                                                    const int* __restrict__ rp,
                                                    const int* __restrict__ col,
                                                    float* __restrict__ out) {
    int lane = threadIdx.x & 63;
    int node = blockIdx.x * 4 + (threadIdx.x >> 6);
    if (node >= NN) return;
    int head = lane >> 4;
    const __half2* v2p = (const __half2*)vv;
    float ax = 0.f, ay = 0.f, l = 0.f;
    int s0 = rp[node], s1 = rp[node + 1];
    int n = s1 - s0;
    int i = 0;
    for (; i + 4 <= n; i += 4) {
        int base = s0 + i;
        int c0 = col[base], c1 = col[base + 1], c2 = col[base + 2], c3 = col[base + 3];
        float w0 = sc[(size_t)base * 4 + head];
        float w1 = sc[(size_t)(base + 1) * 4 + head];
        float w2 = sc[(size_t)(base + 2) * 4 + head];
        float w3 = sc[(size_t)(base + 3) * 4 + head];
        float2 f0 = __half22float2(v2p[(size_t)c0 * 64 + lane]);
        float2 f1 = __half22float2(v2p[(size_t)c1 * 64 + lane]);
        float2 f2 = __half22float2(v2p[(size_t)c2 * 64 + lane]);
        float2 f3 = __half22float2(v2p[(size_t)c3 * 64 + lane]);
        ax += w0 * f0.x; ay += w0 * f0.y;
        ax += w1 * f1.x; ay += w1 * f1.y;
        ax += w2 * f2.x; ay += w2 * f2.y;
        ax += w3 * f3.x; ay += w3 * f3.y;
        l += w0 + w1 + w2 + w3;
    }
    for (; i < n; ++i) {
        int slot = s0 + i;
        float w = sc[(size_t)slot * 4 + head];
        float2 f = __half22float2(v2p[(size_t)col[slot] * 64 + lane]);
        ax += w * f.x; ay += w * f.y; l += w;
    }
    float inv = 1.f / (l + 1e-16f);
    int c = lane * 2;
    float2 st2 = *(const float2*)&sT[(size_t)node * 128 + c];
    *(float2*)&out[(size_t)node * 128 + c] = make_float2(ax * inv + st2.x, ay * inv + st2.y);
}

// ---------------- pooling: per-graph mean + max (batch sorted) ----------------
__global__ __launch_bounds__(128) void k_pool(const float* __restrict__ x,
                                              const int* __restrict__ batch,
                                              float* __restrict__ h) {
    int g = blockIdx.x;
    int lo = 0, hi = NN;
    while (lo < hi) { int mid = (lo + hi) >> 1; if (batch[mid] < g) lo = mid + 1; else hi = mid; }
    int start = lo;
    hi = NN;
    while (lo < hi) { int mid = (lo + hi) >> 1; if (batch[mid] < g + 1) lo = mid + 1; else hi = mid; }
    int end = lo;
    int c = threadIdx.x;
    float s = 0.f, mx = -INFINITY;
    for (int r = start; r < end; ++r) {
        float v = x[(size_t)r * 128 + c];
        s += v; mx = fmaxf(mx, v);
    }
    int cnt = end - start;
    float xm = s / fmaxf((float)cnt, 1.f);
    float xx = (cnt > 0) ? mx : 0.f;
    h[g * 256 + c] = xm;
    h[g * 256 + 128 + c] = xx;
}

// ---------------- head ----------------
__global__ __launch_bounds__(128) void k_head1(const float* __restrict__ h,
                                               const float* __restrict__ W,
                                               const float* __restrict__ b,
                                               float* __restrict__ t1) {
    __shared__ float hr[256];
    int row = blockIdx.x;
    int t = threadIdx.x;
    hr[t] = h[row * 256 + t];
    hr[t + 128] = h[row * 256 + 128 + t];
    __syncthreads();
    float acc = b[t];
#pragma unroll 4
    for (int k = 0; k < 256; ++k) acc += hr[k] * W[k * 128 + t];
    t1[row * 128 + t] = acc;
}

__global__ __launch_bounds__(64) void k_head2(const float* __restrict__ t1,
                                              const float* __restrict__ st,
                                              const float* __restrict__ og,
                                              const float* __restrict__ obe,
                                              const float* __restrict__ W2,
                                              const float* __restrict__ b2,
                                              const float* __restrict__ W3,
                                              const float* __restrict__ b3,
                                              float* __restrict__ out) {
    __shared__ float v[128];
    int row = blockIdx.x, t = threadIdx.x;
    const float invn = 1.f / NG;
#pragma unroll
    for (int half = 0; half < 2; ++half) {
        int ch = t + half * 64;
        float mean = st[ch] * invn;
        float var = fmaxf(st[128 + ch] * invn - mean * mean, 0.f);
        float scv = og[ch] * rsqrtf(var + EPSB);
        float shv = obe[ch] - mean * scv;
        float a = t1[row * 128 + ch] * scv + shv;
        v[ch] = fmaxf(a, 0.f);
    }
    __syncthreads();
    float acc = b2[t];
#pragma unroll 4
    for (int k = 0; k < 128; ++k) acc += v[k] * W2[k * 64 + t];
    float p = fmaxf(acc, 0.f) * W3[t];
    p += __shfl_xor(p, 1); p += __shfl_xor(p, 2); p += __shfl_xor(p, 4);
    p += __shfl_xor(p, 8); p += __shfl_xor(p, 16); p += __shfl_xor(p, 32);
    if (t == 0) out[row] = p + b3[0];
}

// ---------------- launch ----------------
extern "C" void kernel_launch(void* const* d_in, const int* in_sizes, int n_in,
                              void* d_out, int out_size, void* d_ws, size_t ws_size,
                              hipStream_t stream) {
    const float* x_in   = (const float*)d_in[0];
    const int*   ei     = (const int*)d_in[1];
    const int*   batch  = (const int*)d_in[2];
    const float* emb_W  = (const float*)d_in[3];
    const float* emb_b  = (const float*)d_in[4];
    const float* emb_g  = (const float*)d_in[5];
    const float* emb_be = (const float*)d_in[6];
    const float* gWl    = (const float*)d_in[7];
    const float* gWr    = (const float*)d_in[8];
    const float* gbl    = (const float*)d_in[9];
    const float* gbr    = (const float*)d_in[10];
    const float* gatt   = (const float*)d_in[11];
    const float* gbias  = (const float*)d_in[12];
    const float* gg     = (const float*)d_in[13];
    const float* gbe    = (const float*)d_in[14];
    const float* tWq    = (const float*)d_in[15];
    const float* tWk    = (const float*)d_in[16];
    const float* tWv    = (const float*)d_in[17];
    const float* tWs    = (const float*)d_in[18];
    const float* tbq    = (const float*)d_in[19];
    const float* tbk    = (const float*)d_in[20];
    const float* tbv    = (const float*)d_in[21];
    const float* tbs    = (const float*)d_in[22];
    const float* tg     = (const float*)d_in[23];
    const float* tbe    = (const float*)d_in[24];
    const float* oW1    = (const float*)d_in[25];
    const float* ob1    = (const float*)d_in[26];
    const float* og     = (const float*)d_in[27];
    const float* obe    = (const float*)d_in[28];
    const float* oW2    = (const float*)d_in[29];
    const float* ob2    = (const float*)d_in[30];
    const float* oW3    = (const float*)d_in[31];
    const float* ob3    = (const float*)d_in[32];
    float* out = (float*)d_out;

    const size_t NDsz = (size_t)NN * 128;
    float* x     = (float*)d_ws;
    float* bA    = x + NDsz;
    float* bC    = bA + NDsz;
    float* stats = bC + NDsz;        // 7 * 256 floats
    float* hpool = stats + 7 * 256;  // 256*256
    float* t1    = hpool + 65536;    // 256*128
    float* scb   = t1 + 32768;                 // (NE+NN)*4 scores
    __half* xlh  = (__half*)(scb + (size_t)(NE + NN) * 4);  // xl / K
    __half* xrh  = xlh + NDsz;                 // xr / Q
    __half* vh   = xrh + NDsz;                 // V
    short* Wt    = (short*)(vh + NDsz);        // 12 * 128*128 bf16 transposed
    int* deg     = (int*)(Wt + 12 * 16384);
    int* rp      = deg + NN;
    int* cursor  = rp + NN + 1;
    int* colb    = cursor + NN;
    int* dstc    = colb + NE;

    hipMemsetAsync(deg, 0, NN * sizeof(int), stream);
    hipMemsetAsync(stats, 0, 7 * 256 * sizeof(float), stream);

    // weight prep (bf16 transposed)
    k_prep<<<12, 256, 0, stream>>>(gWl, gWr, tWq, tWk, tWv, tWs, Wt);

    // CSR by destination
    k_deg<<<(NE + 255) / 256, 256, 0, stream>>>(ei, deg);
    k_scan<<<1, 1024, 0, stream>>>(deg, rp);
    hipMemcpyAsync(cursor, rp, NN * sizeof(int), hipMemcpyDeviceToDevice, stream);
    k_fill<<<(NE + 255) / 256, 256, 0, stream>>>(ei, cursor, colb, dstc);

    const int gGemm = (NN + 63) / 64;
    const int gStat = (NN + 127) / 128;
    const int gNode = (NN + 3) / 4;
    const int gScG  = ((NE + NN) * 4 + 255) / 256;
    const int gScT  = (NE * 4 + 255) / 256;

    // embedding + BN + relu
    k_gemm_emb<<<gGemm, 256, 0, stream>>>(x_in, emb_W, emb_b, bA, NN);
    k_stats<<<gStat, 256, 0, stream>>>(bA, NN, stats);
    k_bn_apply<<<1024, 256, 0, stream>>>(x, bA, stats, emb_g, emb_be, 1.f / NN, 1, 0);

    // 4 GATv2 layers
    for (int l = 0; l < NL; ++l) {
        k_gemm2<1, 1><<<gGemm, 256, 0, stream>>>(x, Wt + (size_t)l * 16384,
                                                 Wt + (size_t)(4 + l) * 16384,
                                                 gbl + l * 128, gbr + l * 128, xlh, xrh, NN);
        k_gat_score<<<gScG, 256, 0, stream>>>(xlh, xrh, gatt + l * 128, colb, dstc, scb);
        k_gat_aggr<<<gNode, 256, 0, stream>>>(xlh, scb, gbias + l * 128, rp, colb, bC);
        k_stats<<<gStat, 256, 0, stream>>>(bC, NN, stats + (1 + l) * 256);
        k_bn_apply<<<1024, 256, 0, stream>>>(x, bC, stats + (1 + l) * 256, gg + l * 128, gbe + l * 128, 1.f / NN, 1, 1);
    }

    // TransformerConv
    k_gemm2<1, 1><<<gGemm, 256, 0, stream>>>(x, Wt + (size_t)8 * 16384,
                                             Wt + (size_t)9 * 16384, tbq, tbk, xrh, xlh, NN);  // Q, K
    k_gemm2<1, 0><<<gGemm, 256, 0, stream>>>(x, Wt + (size_t)10 * 16384,
                                             Wt + (size_t)11 * 16384, tbv, tbs, vh, bA, NN);   // V, skip
    k_trans_score<<<gScT, 256, 0, stream>>>(xrh, xlh, colb, dstc, scb);
    k_trans_aggr<<<gNode, 256, 0, stream>>>(vh, scb, bA, rp, colb, bC);
    k_stats<<<gStat, 256, 0, stream>>>(bC, NN, stats + 5 * 256);
    k_bn_apply<<<1024, 256, 0, stream>>>(x, bC, stats + 5 * 256, tg, tbe, 1.f / NN, 0, 1);

    // pooling + head
    k_pool<<<NG, 128, 0, stream>>>(x, batch, hpool);
    k_head1<<<NG, 128, 0, stream>>>(hpool, oW1, ob1, t1);
    k_stats<<<(NG + 127) / 128, 256, 0, stream>>>(t1, NG, stats + 6 * 256);
    k_head2<<<NG, 64, 0, stream>>>(t1, stats + 6 * 256, og, obe, oW2, ob2, oW3, ob3, out);
}

// Round 5
// 1222.203 us; speedup vs baseline: 1.2447x; 1.0405x over previous
//
#include <hip/hip_runtime.h>
#include <hip/hip_fp16.h>

// ---------------- constants ----------------
namespace {
constexpr int NN = 50000;   // nodes
constexpr int NE = 800000;  // edges
constexpr int NG = 256;     // graphs
constexpr int NF = 34;      // in features
constexpr int NL = 4;       // GAT layers
constexpr int NB = (NN + 255) / 256;  // scan blocks = 196
}
#define EPSB 1e-5f
#define LSLOPE 0.2f
#define INV_SQRT_C 0.17677669529663687f  // 1/sqrt(32)

typedef short bf16x8 __attribute__((ext_vector_type(8)));
typedef float f32x4 __attribute__((ext_vector_type(4)));

static __device__ __forceinline__ short f2bf(float f) {
    unsigned int u = __float_as_uint(f);
    u = (u + 0x7fff + ((u >> 16) & 1)) >> 16;  // RNE
    return (short)u;
}

// ---------------- CSR build ----------------
__global__ void k_deg(const int* __restrict__ ei, int* __restrict__ deg) {
    int e = blockIdx.x * blockDim.x + threadIdx.x;
    if (e < NE) atomicAdd(&deg[ei[NE + e]], 1);
}

// phase 1: per-block sums
__global__ __launch_bounds__(256) void k_scan1(const int* __restrict__ deg, int* __restrict__ bsum) {
    __shared__ int sm[256];
    int i = blockIdx.x * 256 + threadIdx.x;
    sm[threadIdx.x] = (i < NN) ? deg[i] : 0;
    __syncthreads();
    for (int off = 128; off > 0; off >>= 1) {
        if (threadIdx.x < off) sm[threadIdx.x] += sm[threadIdx.x + off];
        __syncthreads();
    }
    if (threadIdx.x == 0) bsum[blockIdx.x] = sm[0];
}

// phase 2: scan of block sums (NB <= 256), writes exclusive offsets + total
__global__ __launch_bounds__(256) void k_scan2(const int* __restrict__ bsum,
                                               int* __restrict__ boff, int* __restrict__ rp) {
    __shared__ int sm[256];
    int t = threadIdx.x;
    int v = (t < NB) ? bsum[t] : 0;
    sm[t] = v;
    __syncthreads();
    for (int off = 1; off < 256; off <<= 1) {
        int u = (t >= off) ? sm[t - off] : 0;
        __syncthreads();
        sm[t] += u;
        __syncthreads();
    }
    if (t < NB) boff[t] = sm[t] - v;
    if (t == 255) rp[NN] = sm[255];
}

// phase 3: block-local exclusive scan + offset; writes rp and cursor
__global__ __launch_bounds__(256) void k_scan3(const int* __restrict__ deg,
                                               const int* __restrict__ boff,
                                               int* __restrict__ rp, int* __restrict__ cursor) {
    __shared__ int sm[256];
    int i = blockIdx.x * 256 + threadIdx.x;
    int t = threadIdx.x;
    int v = (i < NN) ? deg[i] : 0;
    sm[t] = v;
    __syncthreads();
    for (int off = 1; off < 256; off <<= 1) {
        int u = (t >= off) ? sm[t - off] : 0;
        __syncthreads();
        sm[t] += u;
        __syncthreads();
    }
    if (i < NN) {
        int r = boff[blockIdx.x] + sm[t] - v;
        rp[i] = r;
        cursor[i] = r;
    }
}

__global__ void k_fill(const int* __restrict__ ei, int* __restrict__ cursor,
                       int* __restrict__ col, int* __restrict__ dstc) {
    int e = blockIdx.x * blockDim.x + threadIdx.x;
    if (e < NE) {
        int d = ei[NE + e];
        int p = atomicAdd(&cursor[d], 1);
        col[p] = ei[e];
        dstc[p] = d;
    }
}

// ---------------- weight prep: 12x (128,128) fp32 -> transposed bf16 ----------------
__global__ __launch_bounds__(256) void k_prep(const float* __restrict__ gWl,
                                              const float* __restrict__ gWr,
                                              const float* __restrict__ tWq,
                                              const float* __restrict__ tWk,
                                              const float* __restrict__ tWv,
                                              const float* __restrict__ tWs,
                                              short* __restrict__ dst) {
    int m = blockIdx.x;
    const float* src;
    if (m < 4) src = gWl + m * 16384;
    else if (m < 8) src = gWr + (m - 4) * 16384;
    else if (m == 8) src = tWq;
    else if (m == 9) src = tWk;
    else if (m == 10) src = tWv;
    else src = tWs;
    short* d = dst + m * 16384;
    for (int i = threadIdx.x; i < 16384; i += 256) {
        int n = i >> 7, k = i & 127;
        d[i] = f2bf(src[k * 128 + n]);  // Wt[n][k] = W[k][n]
    }
}

// ---------------- pair-fused MFMA GEMM: A(n,128)fp32 @ {Wt0,Wt1} + bias ----------------
template <int OUTH0, int OUTH1>
__global__ __launch_bounds__(256) void k_gemm2(const float* __restrict__ A,
                                               const short* __restrict__ Wt0,
                                               const short* __restrict__ Wt1,
                                               const float* __restrict__ bias0,
                                               const float* __restrict__ bias1,
                                               void* __restrict__ out0,
                                               void* __restrict__ out1, int nRows) {
    __shared__ short As[64 * 136];
    __shared__ short Bs[128 * 136];
    int r0 = blockIdx.x * 64;
    int rows = nRows - r0; if (rows > 64) rows = 64;
    for (int idx = threadIdx.x; idx < 2048; idx += 256) {
        int r = idx >> 5, c4 = idx & 31;
        float4 v = make_float4(0.f, 0.f, 0.f, 0.f);
        if (r < rows) v = ((const float4*)A)[(size_t)(r0 + r) * 32 + c4];
        short4 s;
        s.x = f2bf(v.x); s.y = f2bf(v.y); s.z = f2bf(v.z); s.w = f2bf(v.w);
        *(short4*)&As[r * 136 + c4 * 4] = s;
    }
    {
        const int4* Wt4 = (const int4*)Wt0;
        for (int idx = threadIdx.x; idx < 2048; idx += 256) {
            int row = idx >> 4, c8 = idx & 15;
            *(int4*)&Bs[row * 136 + c8 * 8] = Wt4[idx];
        }
    }
    __syncthreads();
    int lane = threadIdx.x & 63, wave = threadIdx.x >> 6;
    int n16 = lane & 15, quad = lane >> 4;
    int arow = wave * 16 + n16;
    bf16x8 af[4];
#pragma unroll
    for (int kc = 0; kc < 4; ++kc)
        af[kc] = *(const bf16x8*)&As[arow * 136 + kc * 32 + quad * 8];

    f32x4 acc[8];
#pragma unroll
    for (int ct = 0; ct < 8; ++ct) acc[ct] = (f32x4){0.f, 0.f, 0.f, 0.f};
#pragma unroll
    for (int ct = 0; ct < 8; ++ct)
#pragma unroll
        for (int kc = 0; kc < 4; ++kc) {
            bf16x8 bf = *(const bf16x8*)&Bs[(ct * 16 + n16) * 136 + kc * 32 + quad * 8];
            acc[ct] = __builtin_amdgcn_mfma_f32_16x16x32_bf16(af[kc], bf, acc[ct], 0, 0, 0);
        }
#pragma unroll
    for (int ct = 0; ct < 8; ++ct) {
        int colI = ct * 16 + n16;
        float b = bias0[colI];
#pragma unroll
        for (int reg = 0; reg < 4; ++reg) {
            int r = wave * 16 + quad * 4 + reg;  // C/D: col=lane&15, row=quad*4+reg
            if (r < rows) {
                float v = acc[ct][reg] + b;
                if (OUTH0) ((__half*)out0)[(size_t)(r0 + r) * 128 + colI] = __float2half(v);
                else       ((float*)out0)[(size_t)(r0 + r) * 128 + colI] = v;
            }
        }
    }
    __syncthreads();
    {
        const int4* Wt4 = (const int4*)Wt1;
        for (int idx = threadIdx.x; idx < 2048; idx += 256) {
            int row = idx >> 4, c8 = idx & 15;
            *(int4*)&Bs[row * 136 + c8 * 8] = Wt4[idx];
        }
    }
    __syncthreads();
#pragma unroll
    for (int ct = 0; ct < 8; ++ct) acc[ct] = (f32x4){0.f, 0.f, 0.f, 0.f};
#pragma unroll
    for (int ct = 0; ct < 8; ++ct)
#pragma unroll
        for (int kc = 0; kc < 4; ++kc) {
            bf16x8 bf = *(const bf16x8*)&Bs[(ct * 16 + n16) * 136 + kc * 32 + quad * 8];
            acc[ct] = __builtin_amdgcn_mfma_f32_16x16x32_bf16(af[kc], bf, acc[ct], 0, 0, 0);
        }
#pragma unroll
    for (int ct = 0; ct < 8; ++ct) {
        int colI = ct * 16 + n16;
        float b = bias1[colI];
#pragma unroll
        for (int reg = 0; reg < 4; ++reg) {
            int r = wave * 16 + quad * 4 + reg;
            if (r < rows) {
                float v = acc[ct][reg] + b;
                if (OUTH1) ((__half*)out1)[(size_t)(r0 + r) * 128 + colI] = __float2half(v);
                else       ((float*)out1)[(size_t)(r0 + r) * 128 + colI] = v;
            }
        }
    }
}

// ---------------- GEMM: (n,34) @ (34,128) + bias (fp32 VALU) ----------
__global__ __launch_bounds__(256) void k_gemm_emb(const float* __restrict__ A,
                                                  const float* __restrict__ W,
                                                  const float* __restrict__ bias,
                                                  float* __restrict__ out, int nRows) {
    __shared__ float As[64 * NF];
    int r0 = blockIdx.x * 64;
    int rows = nRows - r0; if (rows > 64) rows = 64;
    int total = rows * NF;
    for (int idx = threadIdx.x; idx < 64 * NF; idx += 256)
        As[idx] = (idx < total) ? A[(size_t)r0 * NF + idx] : 0.f;
    __syncthreads();
    int tx = threadIdx.x & 31, ty = threadIdx.x >> 5;
    const float4* W4 = (const float4*)W;
    float acc[8][4];
#pragma unroll
    for (int j = 0; j < 8; ++j)
#pragma unroll
        for (int i = 0; i < 4; ++i) acc[j][i] = 0.f;
#pragma unroll 2
    for (int k = 0; k < NF; ++k) {
        float4 w = W4[k * 32 + tx];
#pragma unroll
        for (int j = 0; j < 8; ++j) {
            float a = As[(ty * 8 + j) * NF + k];
            acc[j][0] += a * w.x; acc[j][1] += a * w.y;
            acc[j][2] += a * w.z; acc[j][3] += a * w.w;
        }
    }
    float4 b = ((const float4*)bias)[tx];
#pragma unroll
    for (int j = 0; j < 8; ++j) {
        int r = ty * 8 + j;
        if (r < rows) {
            float4 o = make_float4(acc[j][0] + b.x, acc[j][1] + b.y,
                                   acc[j][2] + b.z, acc[j][3] + b.w);
            ((float4*)out)[(size_t)(r0 + r) * 32 + tx] = o;
        }
    }
}

// ---------------- BN statistics (per-column sum / sumsq) ----------------
__global__ __launch_bounds__(256) void k_stats(const float* __restrict__ src, int nRows,
                                               float* __restrict__ st) {
    int c = threadIdx.x & 127;
    int sub = threadIdx.x >> 7;  // 0/1
    int r0 = blockIdx.x * 128;
    int rend = r0 + 128; if (rend > nRows) rend = nRows;
    float s = 0.f, ss = 0.f;
    for (int r = r0 + sub; r < rend; r += 2) {
        float v = src[(size_t)r * 128 + c];
        s += v; ss += v * v;
    }
    atomicAdd(&st[c], s);
    atomicAdd(&st[128 + c], ss);
}

// dst = (doRes ? dst : 0) + maybe_relu(bn(src))  -- finalize folded in
__global__ __launch_bounds__(256) void k_bn_apply(float* __restrict__ dst,
                                                  const float* __restrict__ src,
                                                  const float* __restrict__ st,
                                                  const float* __restrict__ g,
                                                  const float* __restrict__ b,
                                                  float invn, int doRelu, int doRes) {
    int tid = blockIdx.x * blockDim.x + threadIdx.x;
    int cb = (tid & 31) * 4;  // grid-stride is a multiple of 32 -> cb invariant
    float sc[4], sh[4];
#pragma unroll
    for (int k = 0; k < 4; ++k) {
        float mean = st[cb + k] * invn;
        float var = fmaxf(st[128 + cb + k] * invn - mean * mean, 0.f);
        float s = g[cb + k] * rsqrtf(var + EPSB);
        sc[k] = s; sh[k] = b[cb + k] - mean * s;
    }
    const float4* s4 = (const float4*)src;
    float4* d4 = (float4*)dst;
    const int total = NN * 32;
    for (int i = tid; i < total; i += gridDim.x * blockDim.x) {
        float4 v = s4[i];
        v.x = v.x * sc[0] + sh[0]; v.y = v.y * sc[1] + sh[1];
        v.z = v.z * sc[2] + sh[2]; v.w = v.w * sc[3] + sh[3];
        if (doRelu) {
            v.x = fmaxf(v.x, 0.f); v.y = fmaxf(v.y, 0.f);
            v.z = fmaxf(v.z, 0.f); v.w = fmaxf(v.w, 0.f);
        }
        if (doRes) {
            float4 o = d4[i];
            v.x += o.x; v.y += o.y; v.z += o.z; v.w += o.w;
        }
        d4[i] = v;
    }
}

// ---------------- GAT score: one thread per (CSR slot, head), float4 loads ----------
__global__ __launch_bounds__(256) void k_gat_score(const __half* __restrict__ xl,
                                                   const __half* __restrict__ xr,
                                                   const float* __restrict__ att,
                                                   const int* __restrict__ col,
                                                   const int* __restrict__ dstc,
                                                   float* __restrict__ sc) {
    __shared__ float attS[128];
    if (threadIdx.x < 128) attS[threadIdx.x] = att[threadIdx.x];
    __syncthreads();
    int idx = blockIdx.x * 256 + threadIdx.x;
    int slot = idx >> 2, head = idx & 3;
    if (slot >= NE + NN) return;
    int s, d;
    if (slot < NE) { s = col[slot]; d = dstc[slot]; }
    else { s = slot - NE; d = s; }
    const float4* xlp = (const float4*)(xl + (size_t)s * 128 + head * 32);
    const float4* xrp = (const float4*)(xr + (size_t)d * 128 + head * 32);
    const float* aB = &attS[head * 32];
    float acc = 0.f;
#pragma unroll
    for (int q = 0; q < 4; ++q) {
        float4 A = xlp[q], B = xrp[q];
        const __half2* ah = (const __half2*)&A;
        const __half2* bh = (const __half2*)&B;
#pragma unroll
        for (int j = 0; j < 4; ++j) {
            float2 a2 = __half22float2(ah[j]);
            float2 b2 = __half22float2(bh[j]);
            float ex = a2.x + b2.x, ey = a2.y + b2.y;
            ex = fmaxf(ex, 0.f) + LSLOPE * fminf(ex, 0.f);
            ey = fmaxf(ey, 0.f) + LSLOPE * fminf(ey, 0.f);
            acc += ex * aB[q * 8 + 2 * j] + ey * aB[q * 8 + 2 * j + 1];
        }
    }
    sc[idx] = __expf(acc);  // scores bounded; shift-free exp is exact math
}

// ---------------- Transformer score: one thread per (slot, head), float4 loads ------
__global__ __launch_bounds__(256) void k_trans_score(const __half* __restrict__ qh,
                                                     const __half* __restrict__ kh,
                                                     const int* __restrict__ col,
                                                     const int* __restrict__ dstc,
                                                     float* __restrict__ sc) {
    int idx = blockIdx.x * 256 + threadIdx.x;
    int slot = idx >> 2, head = idx & 3;
    if (slot >= NE) return;
    int s = col[slot], d = dstc[slot];
    const float4* qp = (const float4*)(qh + (size_t)d * 128 + head * 32);
    const float4* kp = (const float4*)(kh + (size_t)s * 128 + head * 32);
    float acc = 0.f;
#pragma unroll
    for (int q = 0; q < 4; ++q) {
        float4 A = qp[q], B = kp[q];
        const __half2* ah = (const __half2*)&A;
        const __half2* bh = (const __half2*)&B;
#pragma unroll
        for (int j = 0; j < 4; ++j) {
            float2 a2 = __half22float2(ah[j]);
            float2 b2 = __half22float2(bh[j]);
            acc += a2.x * b2.x + a2.y * b2.y;
        }
    }
    sc[idx] = __expf(acc * INV_SQRT_C);
}

// ---------------- aggregates: wave/node, half-wave per edge (8 B/lane) --------------
// lane&31 handles channels c4=4*(lane&31); lane>>5 picks edge parity.
template <int SELF>
__device__ __forceinline__ void aggr_body(int j, int T, int s0, int node, int head,
                                          int c4, const int* __restrict__ col,
                                          const float* __restrict__ sc,
                                          const __half* __restrict__ feat,
                                          float& a0, float& a1, float& a2, float& a3,
                                          float& l) {
    bool self = SELF && (j == T - 1);
    int slot = s0 + j;
    int src = self ? node : col[slot];
    size_t scIdx = self ? ((size_t)(NE + node) * 4 + head) : ((size_t)slot * 4 + head);
    float w = sc[scIdx];
    float2 raw = *(const float2*)&feat[(size_t)src * 128 + c4];
    float2 f0 = __half22float2(*(const __half2*)&raw.x);
    float2 f1 = __half22float2(*(const __half2*)&raw.y);
    a0 += w * f0.x; a1 += w * f0.y; a2 += w * f1.x; a3 += w * f1.y; l += w;
}

__global__ __launch_bounds__(256) void k_gat_aggr(const __half* __restrict__ xl,
                                                  const float* __restrict__ sc,
                                                  const float* __restrict__ gbias_l,
                                                  const int* __restrict__ rp,
                                                  const int* __restrict__ col,
                                                  float* __restrict__ out) {
    int lane = threadIdx.x & 63;
    int node = blockIdx.x * 4 + (threadIdx.x >> 6);
    if (node >= NN) return;
    int half = lane >> 5;
    int l32 = lane & 31;
    int c4 = l32 * 4;
    int head = l32 >> 3;
    int s0 = rp[node];
    int T = rp[node + 1] - s0 + 1;  // +1: self loop is logical edge T-1
    float a0 = 0.f, a1 = 0.f, a2 = 0.f, a3 = 0.f, l = 0.f;
    int j = half;
    for (; j + 2 < T; j += 4) {
        aggr_body<1>(j, T, s0, node, head, c4, col, sc, xl, a0, a1, a2, a3, l);
        aggr_body<1>(j + 2, T, s0, node, head, c4, col, sc, xl, a0, a1, a2, a3, l);
    }
    for (; j < T; j += 2)
        aggr_body<1>(j, T, s0, node, head, c4, col, sc, xl, a0, a1, a2, a3, l);
    a0 += __shfl_xor(a0, 32); a1 += __shfl_xor(a1, 32);
    a2 += __shfl_xor(a2, 32); a3 += __shfl_xor(a3, 32);
    l += __shfl_xor(l, 32);
    if (half == 0) {
        float inv = 1.f / (l + 1e-16f);
        float4 gb = *(const float4*)&gbias_l[c4];
        float4 o = make_float4(a0 * inv + gb.x, a1 * inv + gb.y,
                               a2 * inv + gb.z, a3 * inv + gb.w);
        *(float4*)&out[(size_t)node * 128 + c4] = o;
    }
}

__global__ __launch_bounds__(256) void k_trans_aggr(const __half* __restrict__ vv,
                                                    const float* __restrict__ sc,
                                                    const float* __restrict__ sT,
                                                    const int* __restrict__ rp,
                                                    const int* __restrict__ col,
                                                    float* __restrict__ out) {
    int lane = threadIdx.x & 63;
    int node = blockIdx.x * 4 + (threadIdx.x >> 6);
    if (node >= NN) return;
    int half = lane >> 5;
    int l32 = lane & 31;
    int c4 = l32 * 4;
    int head = l32 >> 3;
    int s0 = rp[node];
    int T = rp[node + 1] - s0;
    float a0 = 0.f, a1 = 0.f, a2 = 0.f, a3 = 0.f, l = 0.f;
    int j = half;
    for (; j + 2 < T; j += 4) {
        aggr_body<0>(j, T, s0, node, head, c4, col, sc, vv, a0, a1, a2, a3, l);
        aggr_body<0>(j + 2, T, s0, node, head, c4, col, sc, vv, a0, a1, a2, a3, l);
    }
    for (; j < T; j += 2)
        aggr_body<0>(j, T, s0, node, head, c4, col, sc, vv, a0, a1, a2, a3, l);
    a0 += __shfl_xor(a0, 32); a1 += __shfl_xor(a1, 32);
    a2 += __shfl_xor(a2, 32); a3 += __shfl_xor(a3, 32);
    l += __shfl_xor(l, 32);
    if (half == 0) {
        float inv = 1.f / (l + 1e-16f);
        float4 st4 = *(const float4*)&sT[(size_t)node * 128 + c4];
        float4 o = make_float4(a0 * inv + st4.x, a1 * inv + st4.y,
                               a2 * inv + st4.z, a3 * inv + st4.w);
        *(float4*)&out[(size_t)node * 128 + c4] = o;
    }
}

// ---------------- pooling: per-graph mean + max (batch sorted) ----------------
__global__ __launch_bounds__(128) void k_pool(const float* __restrict__ x,
                                              const int* __restrict__ batch,
                                              float* __restrict__ h) {
    int g = blockIdx.x;
    int lo = 0, hi = NN;
    while (lo < hi) { int mid = (lo + hi) >> 1; if (batch[mid] < g) lo = mid + 1; else hi = mid; }
    int start = lo;
    hi = NN;
    while (lo < hi) { int mid = (lo + hi) >> 1; if (batch[mid] < g + 1) lo = mid + 1; else hi = mid; }
    int end = lo;
    int c = threadIdx.x;
    float s = 0.f, mx = -INFINITY;
    for (int r = start; r < end; ++r) {
        float v = x[(size_t)r * 128 + c];
        s += v; mx = fmaxf(mx, v);
    }
    int cnt = end - start;
    float xm = s / fmaxf((float)cnt, 1.f);
    float xx = (cnt > 0) ? mx : 0.f;
    h[g * 256 + c] = xm;
    h[g * 256 + 128 + c] = xx;
}

// ---------------- head ----------------
__global__ __launch_bounds__(128) void k_head1(const float* __restrict__ h,
                                               const float* __restrict__ W,
                                               const float* __restrict__ b,
                                               float* __restrict__ t1) {
    __shared__ float hr[256];
    int row = blockIdx.x;
    int t = threadIdx.x;
    hr[t] = h[row * 256 + t];
    hr[t + 128] = h[row * 256 + 128 + t];
    __syncthreads();
    float acc = b[t];
#pragma unroll 4
    for (int k = 0; k < 256; ++k) acc += hr[k] * W[k * 128 + t];
    t1[row * 128 + t] = acc;
}

__global__ __launch_bounds__(64) void k_head2(const float* __restrict__ t1,
                                              const float* __restrict__ st,
                                              const float* __restrict__ og,
                                              const float* __restrict__ obe,
                                              const float* __restrict__ W2,
                                              const float* __restrict__ b2,
                                              const float* __restrict__ W3,
                                              const float* __restrict__ b3,
                                              float* __restrict__ out) {
    __shared__ float v[128];
    int row = blockIdx.x, t = threadIdx.x;
    const float invn = 1.f / NG;
#pragma unroll
    for (int half = 0; half < 2; ++half) {
        int ch = t + half * 64;
        float mean = st[ch] * invn;
        float var = fmaxf(st[128 + ch] * invn - mean * mean, 0.f);
        float scv = og[ch] * rsqrtf(var + EPSB);
        float shv = obe[ch] - mean * scv;
        float a = t1[row * 128 + ch] * scv + shv;
        v[ch] = fmaxf(a, 0.f);
    }
    __syncthreads();
    float acc = b2[t];
#pragma unroll 4
    for (int k = 0; k < 128; ++k) acc += v[k] * W2[k * 64 + t];
    float p = fmaxf(acc, 0.f) * W3[t];
    p += __shfl_xor(p, 1); p += __shfl_xor(p, 2); p += __shfl_xor(p, 4);
    p += __shfl_xor(p, 8); p += __shfl_xor(p, 16); p += __shfl_xor(p, 32);
    if (t == 0) out[row] = p + b3[0];
}

// ---------------- launch ----------------
extern "C" void kernel_launch(void* const* d_in, const int* in_sizes, int n_in,
                              void* d_out, int out_size, void* d_ws, size_t ws_size,
                              hipStream_t stream) {
    const float* x_in   = (const float*)d_in[0];
    const int*   ei     = (const int*)d_in[1];
    const int*   batch  = (const int*)d_in[2];
    const float* emb_W  = (const float*)d_in[3];
    const float* emb_b  = (const float*)d_in[4];
    const float* emb_g  = (const float*)d_in[5];
    const float* emb_be = (const float*)d_in[6];
    const float* gWl    = (const float*)d_in[7];
    const float* gWr    = (const float*)d_in[8];
    const float* gbl    = (const float*)d_in[9];
    const float* gbr    = (const float*)d_in[10];
    const float* gatt   = (const float*)d_in[11];
    const float* gbias  = (const float*)d_in[12];
    const float* gg     = (const float*)d_in[13];
    const float* gbe    = (const float*)d_in[14];
    const float* tWq    = (const float*)d_in[15];
    const float* tWk    = (const float*)d_in[16];
    const float* tWv    = (const float*)d_in[17];
    const float* tWs    = (const float*)d_in[18];
    const float* tbq    = (const float*)d_in[19];
    const float* tbk    = (const float*)d_in[20];
    const float* tbv    = (const float*)d_in[21];
    const float* tbs    = (const float*)d_in[22];
    const float* tg     = (const float*)d_in[23];
    const float* tbe    = (const float*)d_in[24];
    const float* oW1    = (const float*)d_in[25];
    const float* ob1    = (const float*)d_in[26];
    const float* og     = (const float*)d_in[27];
    const float* obe    = (const float*)d_in[28];
    const float* oW2    = (const float*)d_in[29];
    const float* ob2    = (const float*)d_in[30];
    const float* oW3    = (const float*)d_in[31];
    const float* ob3    = (const float*)d_in[32];
    float* out = (float*)d_out;

    const size_t NDsz = (size_t)NN * 128;
    float* x     = (float*)d_ws;
    float* bA    = x + NDsz;
    float* bC    = bA + NDsz;
    float* stats = bC + NDsz;        // 7 * 256 floats
    float* hpool = stats + 7 * 256;  // 256*256
    float* t1    = hpool + 65536;    // 256*128
    float* scb   = t1 + 32768;                 // (NE+NN)*4 scores
    __half* xlh  = (__half*)(scb + (size_t)(NE + NN) * 4);  // xl / K
    __half* xrh  = xlh + NDsz;                 // xr / Q
    __half* vh   = xrh + NDsz;                 // V
    short* Wt    = (short*)(vh + NDsz);        // 12 * 128*128 bf16 transposed
    int* deg     = (int*)(Wt + 12 * 16384);
    int* rp      = deg + NN;
    int* cursor  = rp + NN + 1;
    int* colb    = cursor + NN;
    int* dstc    = colb + NE + 64;   // +64 pad: speculative col read at self-loop slot
    int* bsum    = dstc + NE;
    int* boff    = bsum + 256;

    hipMemsetAsync(deg, 0, NN * sizeof(int), stream);
    hipMemsetAsync(stats, 0, 7 * 256 * sizeof(float), stream);

    // weight prep (bf16 transposed)
    k_prep<<<12, 256, 0, stream>>>(gWl, gWr, tWq, tWk, tWv, tWs, Wt);

    // CSR by destination (parallel 3-phase scan)
    k_deg<<<(NE + 255) / 256, 256, 0, stream>>>(ei, deg);
    k_scan1<<<NB, 256, 0, stream>>>(deg, bsum);
    k_scan2<<<1, 256, 0, stream>>>(bsum, boff, rp);
    k_scan3<<<NB, 256, 0, stream>>>(deg, boff, rp, cursor);
    k_fill<<<(NE + 255) / 256, 256, 0, stream>>>(ei, cursor, colb, dstc);

    const int gGemm = (NN + 63) / 64;
    const int gStat = (NN + 127) / 128;
    const int gNode = (NN + 3) / 4;
    const int gScG  = ((NE + NN) * 4 + 255) / 256;
    const int gScT  = (NE * 4 + 255) / 256;

    // embedding + BN + relu
    k_gemm_emb<<<gGemm, 256, 0, stream>>>(x_in, emb_W, emb_b, bA, NN);
    k_stats<<<gStat, 256, 0, stream>>>(bA, NN, stats);
    k_bn_apply<<<1024, 256, 0, stream>>>(x, bA, stats, emb_g, emb_be, 1.f / NN, 1, 0);

    // 4 GATv2 layers
    for (int l = 0; l < NL; ++l) {
        k_gemm2<1, 1><<<gGemm, 256, 0, stream>>>(x, Wt + (size_t)l * 16384,
                                                 Wt + (size_t)(4 + l) * 16384,
                                                 gbl + l * 128, gbr + l * 128, xlh, xrh, NN);
        k_gat_score<<<gScG, 256, 0, stream>>>(xlh, xrh, gatt + l * 128, colb, dstc, scb);
        k_gat_aggr<<<gNode, 256, 0, stream>>>(xlh, scb, gbias + l * 128, rp, colb, bC);
        k_stats<<<gStat, 256, 0, stream>>>(bC, NN, stats + (1 + l) * 256);
        k_bn_apply<<<1024, 256, 0, stream>>>(x, bC, stats + (1 + l) * 256, gg + l * 128, gbe + l * 128, 1.f / NN, 1, 1);
    }

    // TransformerConv
    k_gemm2<1, 1><<<gGemm, 256, 0, stream>>>(x, Wt + (size_t)8 * 16384,
                                             Wt + (size_t)9 * 16384, tbq, tbk, xrh, xlh, NN);  // Q, K
    k_gemm2<1, 0><<<gGemm, 256, 0, stream>>>(x, Wt + (size_t)10 * 16384,
                                             Wt + (size_t)11 * 16384, tbv, tbs, vh, bA, NN);   // V, skip
    k_trans_score<<<gScT, 256, 0, stream>>>(xrh, xlh, colb, dstc, scb);
    k_trans_aggr<<<gNode, 256, 0, stream>>>(vh, scb, bA, rp, colb, bC);
    k_stats<<<gStat, 256, 0, stream>>>(bC, NN, stats + 5 * 256);
    k_bn_apply<<<1024, 256, 0, stream>>>(x, bC, stats + 5 * 256, tg, tbe, 1.f / NN, 0, 1);

    // pooling + head
    k_pool<<<NG, 128, 0, stream>>>(x, batch, hpool);
    k_head1<<<NG, 128, 0, stream>>>(hpool, oW1, ob1, t1);
    k_stats<<<(NG + 127) / 128, 256, 0, stream>>>(t1, NG, stats + 6 * 256);
    k_head2<<<NG, 64, 0, stream>>>(t1, stats + 6 * 256, og, obe, oW2, ob2, oW3, ob3, out);
}

// Round 6
// 1156.511 us; speedup vs baseline: 1.3154x; 1.0568x over previous
//
#include <hip/hip_runtime.h>
#include <hip/hip_fp16.h>

// ---------------- constants ----------------
namespace {
constexpr int NN = 50000;   // nodes
constexpr int NE = 800000;  // edges
constexpr int NG = 256;     // graphs
constexpr int NF = 34;      // in features
constexpr int NL = 4;       // GAT layers
constexpr int NB = (NN + 255) / 256;  // scan blocks = 196
}
#define EPSB 1e-5f
#define LSLOPE 0.2f
#define INV_SQRT_C 0.17677669529663687f  // 1/sqrt(32)

typedef short bf16x8 __attribute__((ext_vector_type(8)));
typedef float f32x4 __attribute__((ext_vector_type(4)));

static __device__ __forceinline__ short f2bf(float f) {
    unsigned int u = __float_as_uint(f);
    u = (u + 0x7fff + ((u >> 16) & 1)) >> 16;  // RNE
    return (short)u;
}
// order-preserving float<->uint for atomicMax; all encodings > 0, so memset-0 = -inf
static __device__ __forceinline__ unsigned fenc(float x) {
    unsigned u = __float_as_uint(x);
    return (u & 0x80000000u) ? ~u : (u | 0x80000000u);
}
static __device__ __forceinline__ float fdec(unsigned u) {
    return __uint_as_float((u & 0x80000000u) ? (u ^ 0x80000000u) : ~u);
}

// ---------------- CSR build ----------------
__global__ void k_deg(const int* __restrict__ ei, int* __restrict__ deg) {
    int e = blockIdx.x * blockDim.x + threadIdx.x;
    if (e < NE) atomicAdd(&deg[ei[NE + e]], 1);
}

__global__ __launch_bounds__(256) void k_scan1(const int* __restrict__ deg, int* __restrict__ bsum) {
    __shared__ int sm[256];
    int i = blockIdx.x * 256 + threadIdx.x;
    sm[threadIdx.x] = (i < NN) ? deg[i] : 0;
    __syncthreads();
    for (int off = 128; off > 0; off >>= 1) {
        if (threadIdx.x < off) sm[threadIdx.x] += sm[threadIdx.x + off];
        __syncthreads();
    }
    if (threadIdx.x == 0) bsum[blockIdx.x] = sm[0];
}

__global__ __launch_bounds__(256) void k_scan2(const int* __restrict__ bsum,
                                               int* __restrict__ boff, int* __restrict__ rp) {
    __shared__ int sm[256];
    int t = threadIdx.x;
    int v = (t < NB) ? bsum[t] : 0;
    sm[t] = v;
    __syncthreads();
    for (int off = 1; off < 256; off <<= 1) {
        int u = (t >= off) ? sm[t - off] : 0;
        __syncthreads();
        sm[t] += u;
        __syncthreads();
    }
    if (t < NB) boff[t] = sm[t] - v;
    if (t == 255) rp[NN] = sm[255];
}

__global__ __launch_bounds__(256) void k_scan3(const int* __restrict__ deg,
                                               const int* __restrict__ boff,
                                               int* __restrict__ rp, int* __restrict__ cursor) {
    __shared__ int sm[256];
    int i = blockIdx.x * 256 + threadIdx.x;
    int t = threadIdx.x;
    int v = (i < NN) ? deg[i] : 0;
    sm[t] = v;
    __syncthreads();
    for (int off = 1; off < 256; off <<= 1) {
        int u = (t >= off) ? sm[t - off] : 0;
        __syncthreads();
        sm[t] += u;
        __syncthreads();
    }
    if (i < NN) {
        int r = boff[blockIdx.x] + sm[t] - v;
        rp[i] = r;
        cursor[i] = r;
    }
}

__global__ void k_fill(const int* __restrict__ ei, int* __restrict__ cursor,
                       int* __restrict__ col, int* __restrict__ dstc) {
    int e = blockIdx.x * blockDim.x + threadIdx.x;
    if (e < NE) {
        int d = ei[NE + e];
        int p = atomicAdd(&cursor[d], 1);
        col[p] = ei[e];
        dstc[p] = d;
    }
}

// ---------------- weight prep: 12x (128,128) fp32 -> transposed bf16 ----------------
__global__ __launch_bounds__(256) void k_prep(const float* __restrict__ gWl,
                                              const float* __restrict__ gWr,
                                              const float* __restrict__ tWq,
                                              const float* __restrict__ tWk,
                                              const float* __restrict__ tWv,
                                              const float* __restrict__ tWs,
                                              short* __restrict__ dst) {
    int m = blockIdx.x;
    const float* src;
    if (m < 4) src = gWl + m * 16384;
    else if (m < 8) src = gWr + (m - 4) * 16384;
    else if (m == 8) src = tWq;
    else if (m == 9) src = tWk;
    else if (m == 10) src = tWv;
    else src = tWs;
    short* d = dst + m * 16384;
    for (int i = threadIdx.x; i < 16384; i += 256) {
        int n = i >> 7, k = i & 127;
        d[i] = f2bf(src[k * 128 + n]);  // Wt[n][k] = W[k][n]
    }
}

// ---------------- pair-fused MFMA GEMM: 128 rows/block, B-fragment reuse ------------
// Each wave owns 2 row-tiles (wave*32..+32); one B ds_read feeds 2 MFMAs.
template <int OUTH0, int OUTH1>
__global__ __launch_bounds__(256) void k_gemm2(const float* __restrict__ A,
                                               const short* __restrict__ Wt0,
                                               const short* __restrict__ Wt1,
                                               const float* __restrict__ bias0,
                                               const float* __restrict__ bias1,
                                               void* __restrict__ out0,
                                               void* __restrict__ out1, int nRows) {
    __shared__ short As[128 * 136];
    __shared__ short Bs[128 * 136];
    int r0 = blockIdx.x * 128;
    int rows = nRows - r0; if (rows > 128) rows = 128;
    // stage A (fp32 -> bf16)
    for (int idx = threadIdx.x; idx < 4096; idx += 256) {
        int r = idx >> 5, c4 = idx & 31;
        float4 v = make_float4(0.f, 0.f, 0.f, 0.f);
        if (r < rows) v = ((const float4*)A)[(size_t)(r0 + r) * 32 + c4];
        short4 s;
        s.x = f2bf(v.x); s.y = f2bf(v.y); s.z = f2bf(v.z); s.w = f2bf(v.w);
        *(short4*)&As[r * 136 + c4 * 4] = s;
    }
    // stage B0
    {
        const int4* Wt4 = (const int4*)Wt0;
        for (int idx = threadIdx.x; idx < 2048; idx += 256) {
            int row = idx >> 4, c8 = idx & 15;
            *(int4*)&Bs[row * 136 + c8 * 8] = Wt4[idx];
        }
    }
    __syncthreads();
    int lane = threadIdx.x & 63, wave = threadIdx.x >> 6;
    int n16 = lane & 15, quad = lane >> 4;
    bf16x8 af[2][4];
#pragma unroll
    for (int rt = 0; rt < 2; ++rt)
#pragma unroll
        for (int kc = 0; kc < 4; ++kc)
            af[rt][kc] = *(const bf16x8*)&As[(wave * 32 + rt * 16 + n16) * 136 + kc * 32 + quad * 8];

    f32x4 acc[2][8];
#pragma unroll
    for (int rt = 0; rt < 2; ++rt)
#pragma unroll
        for (int ct = 0; ct < 8; ++ct) acc[rt][ct] = (f32x4){0.f, 0.f, 0.f, 0.f};
#pragma unroll
    for (int ct = 0; ct < 8; ++ct)
#pragma unroll
        for (int kc = 0; kc < 4; ++kc) {
            bf16x8 bf = *(const bf16x8*)&Bs[(ct * 16 + n16) * 136 + kc * 32 + quad * 8];
            acc[0][ct] = __builtin_amdgcn_mfma_f32_16x16x32_bf16(af[0][kc], bf, acc[0][ct], 0, 0, 0);
            acc[1][ct] = __builtin_amdgcn_mfma_f32_16x16x32_bf16(af[1][kc], bf, acc[1][ct], 0, 0, 0);
        }
#pragma unroll
    for (int ct = 0; ct < 8; ++ct) {
        int colI = ct * 16 + n16;
        float b = bias0[colI];
#pragma unroll
        for (int rt = 0; rt < 2; ++rt)
#pragma unroll
            for (int reg = 0; reg < 4; ++reg) {
                int r = wave * 32 + rt * 16 + quad * 4 + reg;  // C/D: col=lane&15, row=quad*4+reg
                if (r < rows) {
                    float v = acc[rt][ct][reg] + b;
                    if (OUTH0) ((__half*)out0)[(size_t)(r0 + r) * 128 + colI] = __float2half(v);
                    else       ((float*)out0)[(size_t)(r0 + r) * 128 + colI] = v;
                }
            }
    }
    __syncthreads();
    // stage B1
    {
        const int4* Wt4 = (const int4*)Wt1;
        for (int idx = threadIdx.x; idx < 2048; idx += 256) {
            int row = idx >> 4, c8 = idx & 15;
            *(int4*)&Bs[row * 136 + c8 * 8] = Wt4[idx];
        }
    }
    __syncthreads();
#pragma unroll
    for (int rt = 0; rt < 2; ++rt)
#pragma unroll
        for (int ct = 0; ct < 8; ++ct) acc[rt][ct] = (f32x4){0.f, 0.f, 0.f, 0.f};
#pragma unroll
    for (int ct = 0; ct < 8; ++ct)
#pragma unroll
        for (int kc = 0; kc < 4; ++kc) {
            bf16x8 bf = *(const bf16x8*)&Bs[(ct * 16 + n16) * 136 + kc * 32 + quad * 8];
            acc[0][ct] = __builtin_amdgcn_mfma_f32_16x16x32_bf16(af[0][kc], bf, acc[0][ct], 0, 0, 0);
            acc[1][ct] = __builtin_amdgcn_mfma_f32_16x16x32_bf16(af[1][kc], bf, acc[1][ct], 0, 0, 0);
        }
#pragma unroll
    for (int ct = 0; ct < 8; ++ct) {
        int colI = ct * 16 + n16;
        float b = bias1[colI];
#pragma unroll
        for (int rt = 0; rt < 2; ++rt)
#pragma unroll
            for (int reg = 0; reg < 4; ++reg) {
                int r = wave * 32 + rt * 16 + quad * 4 + reg;
                if (r < rows) {
                    float v = acc[rt][ct][reg] + b;
                    if (OUTH1) ((__half*)out1)[(size_t)(r0 + r) * 128 + colI] = __float2half(v);
                    else       ((float*)out1)[(size_t)(r0 + r) * 128 + colI] = v;
                }
            }
    }
}

// ---------------- GEMM: (n,34) @ (34,128) + bias (fp32 VALU) ----------
__global__ __launch_bounds__(256) void k_gemm_emb(const float* __restrict__ A,
                                                  const float* __restrict__ W,
                                                  const float* __restrict__ bias,
                                                  float* __restrict__ out, int nRows) {
    __shared__ float As[64 * NF];
    int r0 = blockIdx.x * 64;
    int rows = nRows - r0; if (rows > 64) rows = 64;
    int total = rows * NF;
    for (int idx = threadIdx.x; idx < 64 * NF; idx += 256)
        As[idx] = (idx < total) ? A[(size_t)r0 * NF + idx] : 0.f;
    __syncthreads();
    int tx = threadIdx.x & 31, ty = threadIdx.x >> 5;
    const float4* W4 = (const float4*)W;
    float acc[8][4];
#pragma unroll
    for (int j = 0; j < 8; ++j)
#pragma unroll
        for (int i = 0; i < 4; ++i) acc[j][i] = 0.f;
#pragma unroll 2
    for (int k = 0; k < NF; ++k) {
        float4 w = W4[k * 32 + tx];
#pragma unroll
        for (int j = 0; j < 8; ++j) {
            float a = As[(ty * 8 + j) * NF + k];
            acc[j][0] += a * w.x; acc[j][1] += a * w.y;
            acc[j][2] += a * w.z; acc[j][3] += a * w.w;
        }
    }
    float4 b = ((const float4*)bias)[tx];
#pragma unroll
    for (int j = 0; j < 8; ++j) {
        int r = ty * 8 + j;
        if (r < rows) {
            float4 o = make_float4(acc[j][0] + b.x, acc[j][1] + b.y,
                                   acc[j][2] + b.z, acc[j][3] + b.w);
            ((float4*)out)[(size_t)(r0 + r) * 32 + tx] = o;
        }
    }
}

// ---------------- BN statistics (per-column sum / sumsq) ----------------
__global__ __launch_bounds__(256) void k_stats(const float* __restrict__ src, int nRows,
                                               float* __restrict__ st) {
    int c = threadIdx.x & 127;
    int sub = threadIdx.x >> 7;  // 0/1
    int r0 = blockIdx.x * 128;
    int rend = r0 + 128; if (rend > nRows) rend = nRows;
    float s = 0.f, ss = 0.f;
    for (int r = r0 + sub; r < rend; r += 2) {
        float v = src[(size_t)r * 128 + c];
        s += v; ss += v * v;
    }
    atomicAdd(&st[c], s);
    atomicAdd(&st[128 + c], ss);
}

// dst = (doRes ? dst : 0) + maybe_relu(bn(src))
__global__ __launch_bounds__(256) void k_bn_apply(float* __restrict__ dst,
                                                  const float* __restrict__ src,
                                                  const float* __restrict__ st,
                                                  const float* __restrict__ g,
                                                  const float* __restrict__ b,
                                                  float invn, int doRelu, int doRes) {
    int tid = blockIdx.x * blockDim.x + threadIdx.x;
    int cb = (tid & 31) * 4;
    float sc[4], sh[4];
#pragma unroll
    for (int k = 0; k < 4; ++k) {
        float mean = st[cb + k] * invn;
        float var = fmaxf(st[128 + cb + k] * invn - mean * mean, 0.f);
        float s = g[cb + k] * rsqrtf(var + EPSB);
        sc[k] = s; sh[k] = b[cb + k] - mean * s;
    }
    const float4* s4 = (const float4*)src;
    float4* d4 = (float4*)dst;
    const int total = NN * 32;
    for (int i = tid; i < total; i += gridDim.x * blockDim.x) {
        float4 v = s4[i];
        v.x = v.x * sc[0] + sh[0]; v.y = v.y * sc[1] + sh[1];
        v.z = v.z * sc[2] + sh[2]; v.w = v.w * sc[3] + sh[3];
        if (doRelu) {
            v.x = fmaxf(v.x, 0.f); v.y = fmaxf(v.y, 0.f);
            v.z = fmaxf(v.z, 0.f); v.w = fmaxf(v.w, 0.f);
        }
        if (doRes) {
            float4 o = d4[i];
            v.x += o.x; v.y += o.y; v.z += o.z; v.w += o.w;
        }
        d4[i] = v;
    }
}

// ---------------- GAT score: one thread per (CSR slot, head), float4 loads ----------
__global__ __launch_bounds__(256) void k_gat_score(const __half* __restrict__ xl,
                                                   const __half* __restrict__ xr,
                                                   const float* __restrict__ att,
                                                   const int* __restrict__ col,
                                                   const int* __restrict__ dstc,
                                                   float* __restrict__ sc) {
    __shared__ float attS[128];
    if (threadIdx.x < 128) attS[threadIdx.x] = att[threadIdx.x];
    __syncthreads();
    int idx = blockIdx.x * 256 + threadIdx.x;
    int slot = idx >> 2, head = idx & 3;
    if (slot >= NE + NN) return;
    int s, d;
    if (slot < NE) { s = col[slot]; d = dstc[slot]; }
    else { s = slot - NE; d = s; }
    const float4* xlp = (const float4*)(xl + (size_t)s * 128 + head * 32);
    const float4* xrp = (const float4*)(xr + (size_t)d * 128 + head * 32);
    const float* aB = &attS[head * 32];
    float acc = 0.f;
#pragma unroll
    for (int q = 0; q < 4; ++q) {
        float4 A = xlp[q], B = xrp[q];
        const __half2* ah = (const __half2*)&A;
        const __half2* bh = (const __half2*)&B;
#pragma unroll
        for (int j = 0; j < 4; ++j) {
            float2 a2 = __half22float2(ah[j]);
            float2 b2 = __half22float2(bh[j]);
            float ex = a2.x + b2.x, ey = a2.y + b2.y;
            ex = fmaxf(ex, 0.f) + LSLOPE * fminf(ex, 0.f);
            ey = fmaxf(ey, 0.f) + LSLOPE * fminf(ey, 0.f);
            acc += ex * aB[q * 8 + 2 * j] + ey * aB[q * 8 + 2 * j + 1];
        }
    }
    sc[idx] = __expf(acc);  // scores bounded; shift-free exp is exact math
}

// ---------------- Transformer score ----------------
__global__ __launch_bounds__(256) void k_trans_score(const __half* __restrict__ qh,
                                                     const __half* __restrict__ kh,
                                                     const int* __restrict__ col,
                                                     const int* __restrict__ dstc,
                                                     float* __restrict__ sc) {
    int idx = blockIdx.x * 256 + threadIdx.x;
    int slot = idx >> 2, head = idx & 3;
    if (slot >= NE) return;
    int s = col[slot], d = dstc[slot];
    const float4* qp = (const float4*)(qh + (size_t)d * 128 + head * 32);
    const float4* kp = (const float4*)(kh + (size_t)s * 128 + head * 32);
    float acc = 0.f;
#pragma unroll
    for (int q = 0; q < 4; ++q) {
        float4 A = qp[q], B = kp[q];
        const __half2* ah = (const __half2*)&A;
        const __half2* bh = (const __half2*)&B;
#pragma unroll
        for (int j = 0; j < 4; ++j) {
            float2 a2 = __half22float2(ah[j]);
            float2 b2 = __half22float2(bh[j]);
            acc += a2.x * b2.x + a2.y * b2.y;
        }
    }
    sc[idx] = __expf(acc * INV_SQRT_C);
}

// ---------------- aggregates: wave/node, half-wave per edge (8 B/lane) --------------
template <int SELF>
__device__ __forceinline__ void aggr_body(int j, int T, int s0, int node, int head,
                                          int c4, const int* __restrict__ col,
                                          const float* __restrict__ sc,
                                          const __half* __restrict__ feat,
                                          float& a0, float& a1, float& a2, float& a3,
                                          float& l) {
    bool self = SELF && (j == T - 1);
    int slot = s0 + j;
    int src = self ? node : col[slot];
    size_t scIdx = self ? ((size_t)(NE + node) * 4 + head) : ((size_t)slot * 4 + head);
    float w = sc[scIdx];
    float2 raw = *(const float2*)&feat[(size_t)src * 128 + c4];
    float2 f0 = __half22float2(*(const __half2*)&raw.x);
    float2 f1 = __half22float2(*(const __half2*)&raw.y);
    a0 += w * f0.x; a1 += w * f0.y; a2 += w * f1.x; a3 += w * f1.y; l += w;
}

__global__ __launch_bounds__(256) void k_gat_aggr(const __half* __restrict__ xl,
                                                  const float* __restrict__ sc,
                                                  const float* __restrict__ gbias_l,
                                                  const int* __restrict__ rp,
                                                  const int* __restrict__ col,
                                                  float* __restrict__ out) {
    int lane = threadIdx.x & 63;
    int node = blockIdx.x * 4 + (threadIdx.x >> 6);
    if (node >= NN) return;
    int half = lane >> 5;
    int l32 = lane & 31;
    int c4 = l32 * 4;
    int head = l32 >> 3;
    int s0 = rp[node];
    int T = rp[node + 1] - s0 + 1;  // +1: self loop is logical edge T-1
    float a0 = 0.f, a1 = 0.f, a2 = 0.f, a3 = 0.f, l = 0.f;
    int j = half;
    for (; j + 6 < T; j += 8) {
        aggr_body<1>(j, T, s0, node, head, c4, col, sc, xl, a0, a1, a2, a3, l);
        aggr_body<1>(j + 2, T, s0, node, head, c4, col, sc, xl, a0, a1, a2, a3, l);
        aggr_body<1>(j + 4, T, s0, node, head, c4, col, sc, xl, a0, a1, a2, a3, l);
        aggr_body<1>(j + 6, T, s0, node, head, c4, col, sc, xl, a0, a1, a2, a3, l);
    }
    for (; j < T; j += 2)
        aggr_body<1>(j, T, s0, node, head, c4, col, sc, xl, a0, a1, a2, a3, l);
    a0 += __shfl_xor(a0, 32); a1 += __shfl_xor(a1, 32);
    a2 += __shfl_xor(a2, 32); a3 += __shfl_xor(a3, 32);
    l += __shfl_xor(l, 32);
    if (half == 0) {
        float inv = 1.f / (l + 1e-16f);
        float4 gb = *(const float4*)&gbias_l[c4];
        float4 o = make_float4(a0 * inv + gb.x, a1 * inv + gb.y,
                               a2 * inv + gb.z, a3 * inv + gb.w);
        *(float4*)&out[(size_t)node * 128 + c4] = o;
    }
}

__global__ __launch_bounds__(256) void k_trans_aggr(const __half* __restrict__ vv,
                                                    const float* __restrict__ sc,
                                                    const float* __restrict__ sT,
                                                    const int* __restrict__ rp,
                                                    const int* __restrict__ col,
                                                    float* __restrict__ out) {
    int lane = threadIdx.x & 63;
    int node = blockIdx.x * 4 + (threadIdx.x >> 6);
    if (node >= NN) return;
    int half = lane >> 5;
    int l32 = lane & 31;
    int c4 = l32 * 4;
    int head = l32 >> 3;
    int s0 = rp[node];
    int T = rp[node + 1] - s0;
    float a0 = 0.f, a1 = 0.f, a2 = 0.f, a3 = 0.f, l = 0.f;
    int j = half;
    for (; j + 6 < T; j += 8) {
        aggr_body<0>(j, T, s0, node, head, c4, col, sc, vv, a0, a1, a2, a3, l);
        aggr_body<0>(j + 2, T, s0, node, head, c4, col, sc, vv, a0, a1, a2, a3, l);
        aggr_body<0>(j + 4, T, s0, node, head, c4, col, sc, vv, a0, a1, a2, a3, l);
        aggr_body<0>(j + 6, T, s0, node, head, c4, col, sc, vv, a0, a1, a2, a3, l);
    }
    for (; j < T; j += 2)
        aggr_body<0>(j, T, s0, node, head, c4, col, sc, vv, a0, a1, a2, a3, l);
    a0 += __shfl_xor(a0, 32); a1 += __shfl_xor(a1, 32);
    a2 += __shfl_xor(a2, 32); a3 += __shfl_xor(a3, 32);
    l += __shfl_xor(l, 32);
    if (half == 0) {
        float inv = 1.f / (l + 1e-16f);
        float4 st4 = *(const float4*)&sT[(size_t)node * 128 + c4];
        float4 o = make_float4(a0 * inv + st4.x, a1 * inv + st4.y,
                               a2 * inv + st4.z, a3 * inv + st4.w);
        *(float4*)&out[(size_t)node * 128 + c4] = o;
    }
}

// ---------------- pooling phase 1: node-parallel partials (batch sorted) ------------
__global__ __launch_bounds__(256) void k_pool_part(const float* __restrict__ x,
                                                   const int* __restrict__ batch,
                                                   float* __restrict__ psum,
                                                   unsigned* __restrict__ pmax) {
    __shared__ int bs[64];
    int r0 = blockIdx.x * 64;
    if (threadIdx.x < 64) {
        int r = r0 + threadIdx.x;
        bs[threadIdx.x] = (r < NN) ? batch[r] : -1;
    }
    __syncthreads();
    int c = threadIdx.x & 127;
    int sub = threadIdx.x >> 7;
    int curg = -1;
    float s = 0.f, fmx = -INFINITY;
    for (int i = sub; i < 64; i += 2) {
        int r = r0 + i;
        if (r >= NN) break;
        int g = bs[i];
        if (g != curg) {
            if (curg >= 0) {
                atomicAdd(&psum[curg * 128 + c], s);
                atomicMax(&pmax[curg * 128 + c], fenc(fmx));
            }
            curg = g; s = 0.f; fmx = -INFINITY;
        }
        float v = x[(size_t)r * 128 + c];
        s += v; fmx = fmaxf(fmx, v);
    }
    if (curg >= 0) {
        atomicAdd(&psum[curg * 128 + c], s);
        atomicMax(&pmax[curg * 128 + c], fenc(fmx));
    }
}

// ---------------- pooling phase 2: finalize ----------------
__global__ __launch_bounds__(128) void k_pool_final(const float* __restrict__ psum,
                                                    const unsigned* __restrict__ pmax,
                                                    const int* __restrict__ batch,
                                                    float* __restrict__ h) {
    __shared__ int se[2];
    int g = blockIdx.x;
    if (threadIdx.x == 0) {
        int lo = 0, hi = NN;
        while (lo < hi) { int mid = (lo + hi) >> 1; if (batch[mid] < g) lo = mid + 1; else hi = mid; }
        se[0] = lo;
        hi = NN;
        while (lo < hi) { int mid = (lo + hi) >> 1; if (batch[mid] < g + 1) lo = mid + 1; else hi = mid; }
        se[1] = lo;
    }
    __syncthreads();
    int cnt = se[1] - se[0];
    int c = threadIdx.x;
    float xm = psum[g * 128 + c] / fmaxf((float)cnt, 1.f);
    float xx = (cnt > 0) ? fdec(pmax[g * 128 + c]) : 0.f;
    h[g * 256 + c] = xm;
    h[g * 256 + 128 + c] = xx;
}

// ---------------- head ----------------
__global__ __launch_bounds__(128) void k_head1(const float* __restrict__ h,
                                               const float* __restrict__ W,
                                               const float* __restrict__ b,
                                               float* __restrict__ t1) {
    __shared__ float hr[256];
    int row = blockIdx.x;
    int t = threadIdx.x;
    hr[t] = h[row * 256 + t];
    hr[t + 128] = h[row * 256 + 128 + t];
    __syncthreads();
    float acc = b[t];
#pragma unroll 4
    for (int k = 0; k < 256; ++k) acc += hr[k] * W[k * 128 + t];
    t1[row * 128 + t] = acc;
}

__global__ __launch_bounds__(64) void k_head2(const float* __restrict__ t1,
                                              const float* __restrict__ st,
                                              const float* __restrict__ og,
                                              const float* __restrict__ obe,
                                              const float* __restrict__ W2,
                                              const float* __restrict__ b2,
                                              const float* __restrict__ W3,
                                              const float* __restrict__ b3,
                                              float* __restrict__ out) {
    __shared__ float v[128];
    int row = blockIdx.x, t = threadIdx.x;
    const float invn = 1.f / NG;
#pragma unroll
    for (int half = 0; half < 2; ++half) {
        int ch = t + half * 64;
        float mean = st[ch] * invn;
        float var = fmaxf(st[128 + ch] * invn - mean * mean, 0.f);
        float scv = og[ch] * rsqrtf(var + EPSB);
        float shv = obe[ch] - mean * scv;
        float a = t1[row * 128 + ch] * scv + shv;
        v[ch] = fmaxf(a, 0.f);
    }
    __syncthreads();
    float acc = b2[t];
#pragma unroll 4
    for (int k = 0; k < 128; ++k) acc += v[k] * W2[k * 64 + t];
    float p = fmaxf(acc, 0.f) * W3[t];
    p += __shfl_xor(p, 1); p += __shfl_xor(p, 2); p += __shfl_xor(p, 4);
    p += __shfl_xor(p, 8); p += __shfl_xor(p, 16); p += __shfl_xor(p, 32);
    if (t == 0) out[row] = p + b3[0];
}

// ---------------- launch ----------------
extern "C" void kernel_launch(void* const* d_in, const int* in_sizes, int n_in,
                              void* d_out, int out_size, void* d_ws, size_t ws_size,
                              hipStream_t stream) {
    const float* x_in   = (const float*)d_in[0];
    const int*   ei     = (const int*)d_in[1];
    const int*   batch  = (const int*)d_in[2];
    const float* emb_W  = (const float*)d_in[3];
    const float* emb_b  = (const float*)d_in[4];
    const float* emb_g  = (const float*)d_in[5];
    const float* emb_be = (const float*)d_in[6];
    const float* gWl    = (const float*)d_in[7];
    const float* gWr    = (const float*)d_in[8];
    const float* gbl    = (const float*)d_in[9];
    const float* gbr    = (const float*)d_in[10];
    const float* gatt   = (const float*)d_in[11];
    const float* gbias  = (const float*)d_in[12];
    const float* gg     = (const float*)d_in[13];
    const float* gbe    = (const float*)d_in[14];
    const float* tWq    = (const float*)d_in[15];
    const float* tWk    = (const float*)d_in[16];
    const float* tWv    = (const float*)d_in[17];
    const float* tWs    = (const float*)d_in[18];
    const float* tbq    = (const float*)d_in[19];
    const float* tbk    = (const float*)d_in[20];
    const float* tbv    = (const float*)d_in[21];
    const float* tbs    = (const float*)d_in[22];
    const float* tg     = (const float*)d_in[23];
    const float* tbe    = (const float*)d_in[24];
    const float* oW1    = (const float*)d_in[25];
    const float* ob1    = (const float*)d_in[26];
    const float* og     = (const float*)d_in[27];
    const float* obe    = (const float*)d_in[28];
    const float* oW2    = (const float*)d_in[29];
    const float* ob2    = (const float*)d_in[30];
    const float* oW3    = (const float*)d_in[31];
    const float* ob3    = (const float*)d_in[32];
    float* out = (float*)d_out;

    const size_t NDsz = (size_t)NN * 128;
    float* x     = (float*)d_ws;
    float* bA    = x + NDsz;
    float* bC    = bA + NDsz;
    float* stats = bC + NDsz;        // 7 * 256 floats
    float* hpool = stats + 7 * 256;  // 256*256
    float* t1    = hpool + 65536;    // 256*128
    float* scb   = t1 + 32768;                 // (NE+NN)*4 scores
    __half* xlh  = (__half*)(scb + (size_t)(NE + NN) * 4);  // xl / K
    __half* xrh  = xlh + NDsz;                 // xr / Q
    __half* vh   = xrh + NDsz;                 // V
    short* Wt    = (short*)(vh + NDsz);        // 12 * 128*128 bf16 transposed
    int* deg     = (int*)(Wt + 12 * 16384);
    int* rp      = deg + NN;
    int* cursor  = rp + NN + 1;
    int* colb    = cursor + NN;
    int* dstc    = colb + NE + 64;   // +64 pad: speculative col read at self-loop slot
    int* bsum    = dstc + NE;
    int* boff    = bsum + 256;
    float* psum  = (float*)(boff + 256);     // NG*128
    unsigned* pmax = (unsigned*)(psum + NG * 128);  // NG*128

    hipMemsetAsync(deg, 0, NN * sizeof(int), stream);
    hipMemsetAsync(stats, 0, 7 * 256 * sizeof(float), stream);
    hipMemsetAsync(psum, 0, NG * 128 * 2 * sizeof(float), stream);  // psum + pmax

    // weight prep (bf16 transposed)
    k_prep<<<12, 256, 0, stream>>>(gWl, gWr, tWq, tWk, tWv, tWs, Wt);

    // CSR by destination (parallel 3-phase scan)
    k_deg<<<(NE + 255) / 256, 256, 0, stream>>>(ei, deg);
    k_scan1<<<NB, 256, 0, stream>>>(deg, bsum);
    k_scan2<<<1, 256, 0, stream>>>(bsum, boff, rp);
    k_scan3<<<NB, 256, 0, stream>>>(deg, boff, rp, cursor);
    k_fill<<<(NE + 255) / 256, 256, 0, stream>>>(ei, cursor, colb, dstc);

    const int gEmb  = (NN + 63) / 64;
    const int gGemm = (NN + 127) / 128;
    const int gStat = (NN + 127) / 128;
    const int gNode = (NN + 3) / 4;
    const int gScG  = ((NE + NN) * 4 + 255) / 256;
    const int gScT  = (NE * 4 + 255) / 256;
    const int gPool = (NN + 63) / 64;

    // embedding + BN + relu
    k_gemm_emb<<<gEmb, 256, 0, stream>>>(x_in, emb_W, emb_b, bA, NN);
    k_stats<<<gStat, 256, 0, stream>>>(bA, NN, stats);
    k_bn_apply<<<1024, 256, 0, stream>>>(x, bA, stats, emb_g, emb_be, 1.f / NN, 1, 0);

    // 4 GATv2 layers
    for (int l = 0; l < NL; ++l) {
        k_gemm2<1, 1><<<gGemm, 256, 0, stream>>>(x, Wt + (size_t)l * 16384,
                                                 Wt + (size_t)(4 + l) * 16384,
                                                 gbl + l * 128, gbr + l * 128, xlh, xrh, NN);
        k_gat_score<<<gScG, 256, 0, stream>>>(xlh, xrh, gatt + l * 128, colb, dstc, scb);
        k_gat_aggr<<<gNode, 256, 0, stream>>>(xlh, scb, gbias + l * 128, rp, colb, bC);
        k_stats<<<gStat, 256, 0, stream>>>(bC, NN, stats + (1 + l) * 256);
        k_bn_apply<<<1024, 256, 0, stream>>>(x, bC, stats + (1 + l) * 256, gg + l * 128, gbe + l * 128, 1.f / NN, 1, 1);
    }

    // TransformerConv
    k_gemm2<1, 1><<<gGemm, 256, 0, stream>>>(x, Wt + (size_t)8 * 16384,
                                             Wt + (size_t)9 * 16384, tbq, tbk, xrh, xlh, NN);  // Q, K
    k_gemm2<1, 0><<<gGemm, 256, 0, stream>>>(x, Wt + (size_t)10 * 16384,
                                             Wt + (size_t)11 * 16384, tbv, tbs, vh, bA, NN);   // V, skip
    k_trans_score<<<gScT, 256, 0, stream>>>(xrh, xlh, colb, dstc, scb);
    k_trans_aggr<<<gNode, 256, 0, stream>>>(vh, scb, bA, rp, colb, bC);
    k_stats<<<gStat, 256, 0, stream>>>(bC, NN, stats + 5 * 256);
    k_bn_apply<<<1024, 256, 0, stream>>>(x, bC, stats + 5 * 256, tg, tbe, 1.f / NN, 0, 1);

    // pooling + head
    k_pool_part<<<gPool, 256, 0, stream>>>(x, batch, psum, pmax);
    k_pool_final<<<NG, 128, 0, stream>>>(psum, pmax, batch, hpool);
    k_head1<<<NG, 128, 0, stream>>>(hpool, oW1, ob1, t1);
    k_stats<<<(NG + 127) / 128, 256, 0, stream>>>(t1, NG, stats + 6 * 256);
    k_head2<<<NG, 64, 0, stream>>>(t1, stats + 6 * 256, og, obe, oW2, ob2, oW3, ob3, out);
}

// Round 7
// 1149.928 us; speedup vs baseline: 1.3230x; 1.0057x over previous
//
#include <hip/hip_runtime.h>
#include <hip/hip_fp16.h>

// ---------------- constants ----------------
namespace {
constexpr int NN = 50000;   // nodes
constexpr int NE = 800000;  // edges
constexpr int NG = 256;     // graphs
constexpr int NF = 34;      // in features
constexpr int NL = 4;       // GAT layers
constexpr int NB = (NN + 255) / 256;  // scan blocks = 196
}
#define EPSB 1e-5f
#define LSLOPE 0.2f
#define INV_SQRT_C 0.17677669529663687f  // 1/sqrt(32)

typedef short bf16x8 __attribute__((ext_vector_type(8)));
typedef float f32x4 __attribute__((ext_vector_type(4)));

static __device__ __forceinline__ short f2bf(float f) {
    unsigned int u = __float_as_uint(f);
    u = (u + 0x7fff + ((u >> 16) & 1)) >> 16;  // RNE
    return (short)u;
}
// order-preserving float<->uint for atomicMax; all encodings > 0, so memset-0 = -inf
static __device__ __forceinline__ unsigned fenc(float x) {
    unsigned u = __float_as_uint(x);
    return (u & 0x80000000u) ? ~u : (u | 0x80000000u);
}
static __device__ __forceinline__ float fdec(unsigned u) {
    return __uint_as_float((u & 0x80000000u) ? (u ^ 0x80000000u) : ~u);
}

// ---------------- CSR build ----------------
__global__ void k_deg(const int* __restrict__ ei, int* __restrict__ deg) {
    int e = blockIdx.x * blockDim.x + threadIdx.x;
    if (e < NE) atomicAdd(&deg[ei[NE + e]], 1);
}

__global__ __launch_bounds__(256) void k_scan1(const int* __restrict__ deg, int* __restrict__ bsum) {
    __shared__ int sm[256];
    int i = blockIdx.x * 256 + threadIdx.x;
    sm[threadIdx.x] = (i < NN) ? deg[i] : 0;
    __syncthreads();
    for (int off = 128; off > 0; off >>= 1) {
        if (threadIdx.x < off) sm[threadIdx.x] += sm[threadIdx.x + off];
        __syncthreads();
    }
    if (threadIdx.x == 0) bsum[blockIdx.x] = sm[0];
}

__global__ __launch_bounds__(256) void k_scan2(const int* __restrict__ bsum,
                                               int* __restrict__ boff, int* __restrict__ rp) {
    __shared__ int sm[256];
    int t = threadIdx.x;
    int v = (t < NB) ? bsum[t] : 0;
    sm[t] = v;
    __syncthreads();
    for (int off = 1; off < 256; off <<= 1) {
        int u = (t >= off) ? sm[t - off] : 0;
        __syncthreads();
        sm[t] += u;
        __syncthreads();
    }
    if (t < NB) boff[t] = sm[t] - v;
    if (t == 255) rp[NN] = sm[255];
}

__global__ __launch_bounds__(256) void k_scan3(const int* __restrict__ deg,
                                               const int* __restrict__ boff,
                                               int* __restrict__ rp, int* __restrict__ cursor) {
    __shared__ int sm[256];
    int i = blockIdx.x * 256 + threadIdx.x;
    int t = threadIdx.x;
    int v = (i < NN) ? deg[i] : 0;
    sm[t] = v;
    __syncthreads();
    for (int off = 1; off < 256; off <<= 1) {
        int u = (t >= off) ? sm[t - off] : 0;
        __syncthreads();
        sm[t] += u;
        __syncthreads();
    }
    if (i < NN) {
        int r = boff[blockIdx.x] + sm[t] - v;
        rp[i] = r;
        cursor[i] = r;
    }
}

// single int2 scatter per edge (src,dst packed -> one dirtied line instead of two)
__global__ void k_fill(const int* __restrict__ ei, int* __restrict__ cursor,
                       int2* __restrict__ edg) {
    int e = blockIdx.x * blockDim.x + threadIdx.x;
    if (e < NE) {
        int s = ei[e];
        int d = ei[NE + e];
        int p = atomicAdd(&cursor[d], 1);
        edg[p] = make_int2(s, d);
    }
}

// ---------------- weight prep: 12x (128,128) fp32 -> transposed bf16 ----------------
__global__ __launch_bounds__(256) void k_prep(const float* __restrict__ gWl,
                                              const float* __restrict__ gWr,
                                              const float* __restrict__ tWq,
                                              const float* __restrict__ tWk,
                                              const float* __restrict__ tWv,
                                              const float* __restrict__ tWs,
                                              short* __restrict__ dst) {
    int m = blockIdx.x;
    const float* src;
    if (m < 4) src = gWl + m * 16384;
    else if (m < 8) src = gWr + (m - 4) * 16384;
    else if (m == 8) src = tWq;
    else if (m == 9) src = tWk;
    else if (m == 10) src = tWv;
    else src = tWs;
    short* d = dst + m * 16384;
    for (int i = threadIdx.x; i < 16384; i += 256) {
        int n = i >> 7, k = i & 127;
        d[i] = f2bf(src[k * 128 + n]);  // Wt[n][k] = W[k][n]
    }
}

// ---------------- pair-fused MFMA GEMM: bf16 A input, 128 rows/block ----------------
template <int OUTH0, int OUTH1>
__global__ __launch_bounds__(256) void k_gemm2(const short* __restrict__ A,  // bf16
                                               const short* __restrict__ Wt0,
                                               const short* __restrict__ Wt1,
                                               const float* __restrict__ bias0,
                                               const float* __restrict__ bias1,
                                               void* __restrict__ out0,
                                               void* __restrict__ out1, int nRows) {
    __shared__ short As[128 * 136];
    __shared__ short Bs[128 * 136];
    int r0 = blockIdx.x * 128;
    int rows = nRows - r0; if (rows > 128) rows = 128;
    // stage A (bf16, 16B loads)
    {
        const int4* A4 = (const int4*)A;  // 8 shorts each
        for (int idx = threadIdx.x; idx < 2048; idx += 256) {
            int r = idx >> 4, c8 = idx & 15;
            int4 v = make_int4(0, 0, 0, 0);
            if (r < rows) v = A4[(size_t)(r0 + r) * 16 + c8];
            *(int4*)&As[r * 136 + c8 * 8] = v;
        }
    }
    // stage B0
    {
        const int4* Wt4 = (const int4*)Wt0;
        for (int idx = threadIdx.x; idx < 2048; idx += 256) {
            int row = idx >> 4, c8 = idx & 15;
            *(int4*)&Bs[row * 136 + c8 * 8] = Wt4[idx];
        }
    }
    __syncthreads();
    int lane = threadIdx.x & 63, wave = threadIdx.x >> 6;
    int n16 = lane & 15, quad = lane >> 4;
    bf16x8 af[2][4];
#pragma unroll
    for (int rt = 0; rt < 2; ++rt)
#pragma unroll
        for (int kc = 0; kc < 4; ++kc)
            af[rt][kc] = *(const bf16x8*)&As[(wave * 32 + rt * 16 + n16) * 136 + kc * 32 + quad * 8];

    f32x4 acc[2][8];
#pragma unroll
    for (int rt = 0; rt < 2; ++rt)
#pragma unroll
        for (int ct = 0; ct < 8; ++ct) acc[rt][ct] = (f32x4){0.f, 0.f, 0.f, 0.f};
#pragma unroll
    for (int ct = 0; ct < 8; ++ct)
#pragma unroll
        for (int kc = 0; kc < 4; ++kc) {
            bf16x8 bf = *(const bf16x8*)&Bs[(ct * 16 + n16) * 136 + kc * 32 + quad * 8];
            acc[0][ct] = __builtin_amdgcn_mfma_f32_16x16x32_bf16(af[0][kc], bf, acc[0][ct], 0, 0, 0);
            acc[1][ct] = __builtin_amdgcn_mfma_f32_16x16x32_bf16(af[1][kc], bf, acc[1][ct], 0, 0, 0);
        }
#pragma unroll
    for (int ct = 0; ct < 8; ++ct) {
        int colI = ct * 16 + n16;
        float b = bias0[colI];
#pragma unroll
        for (int rt = 0; rt < 2; ++rt)
#pragma unroll
            for (int reg = 0; reg < 4; ++reg) {
                int r = wave * 32 + rt * 16 + quad * 4 + reg;  // C/D: col=lane&15, row=quad*4+reg
                if (r < rows) {
                    float v = acc[rt][ct][reg] + b;
                    if (OUTH0) ((__half*)out0)[(size_t)(r0 + r) * 128 + colI] = __float2half(v);
                    else       ((float*)out0)[(size_t)(r0 + r) * 128 + colI] = v;
                }
            }
    }
    __syncthreads();
    // stage B1
    {
        const int4* Wt4 = (const int4*)Wt1;
        for (int idx = threadIdx.x; idx < 2048; idx += 256) {
            int row = idx >> 4, c8 = idx & 15;
            *(int4*)&Bs[row * 136 + c8 * 8] = Wt4[idx];
        }
    }
    __syncthreads();
#pragma unroll
    for (int rt = 0; rt < 2; ++rt)
#pragma unroll
        for (int ct = 0; ct < 8; ++ct) acc[rt][ct] = (f32x4){0.f, 0.f, 0.f, 0.f};
#pragma unroll
    for (int ct = 0; ct < 8; ++ct)
#pragma unroll
        for (int kc = 0; kc < 4; ++kc) {
            bf16x8 bf = *(const bf16x8*)&Bs[(ct * 16 + n16) * 136 + kc * 32 + quad * 8];
            acc[0][ct] = __builtin_amdgcn_mfma_f32_16x16x32_bf16(af[0][kc], bf, acc[0][ct], 0, 0, 0);
            acc[1][ct] = __builtin_amdgcn_mfma_f32_16x16x32_bf16(af[1][kc], bf, acc[1][ct], 0, 0, 0);
        }
#pragma unroll
    for (int ct = 0; ct < 8; ++ct) {
        int colI = ct * 16 + n16;
        float b = bias1[colI];
#pragma unroll
        for (int rt = 0; rt < 2; ++rt)
#pragma unroll
            for (int reg = 0; reg < 4; ++reg) {
                int r = wave * 32 + rt * 16 + quad * 4 + reg;
                if (r < rows) {
                    float v = acc[rt][ct][reg] + b;
                    if (OUTH1) ((__half*)out1)[(size_t)(r0 + r) * 128 + colI] = __float2half(v);
                    else       ((float*)out1)[(size_t)(r0 + r) * 128 + colI] = v;
                }
            }
    }
}

// ---------------- GEMM: (n,34) @ (34,128) + bias (fp32 VALU) ----------
__global__ __launch_bounds__(256) void k_gemm_emb(const float* __restrict__ A,
                                                  const float* __restrict__ W,
                                                  const float* __restrict__ bias,
                                                  float* __restrict__ out, int nRows) {
    __shared__ float As[64 * NF];
    int r0 = blockIdx.x * 64;
    int rows = nRows - r0; if (rows > 64) rows = 64;
    int total = rows * NF;
    for (int idx = threadIdx.x; idx < 64 * NF; idx += 256)
        As[idx] = (idx < total) ? A[(size_t)r0 * NF + idx] : 0.f;
    __syncthreads();
    int tx = threadIdx.x & 31, ty = threadIdx.x >> 5;
    const float4* W4 = (const float4*)W;
    float acc[8][4];
#pragma unroll
    for (int j = 0; j < 8; ++j)
#pragma unroll
        for (int i = 0; i < 4; ++i) acc[j][i] = 0.f;
#pragma unroll 2
    for (int k = 0; k < NF; ++k) {
        float4 w = W4[k * 32 + tx];
#pragma unroll
        for (int j = 0; j < 8; ++j) {
            float a = As[(ty * 8 + j) * NF + k];
            acc[j][0] += a * w.x; acc[j][1] += a * w.y;
            acc[j][2] += a * w.z; acc[j][3] += a * w.w;
        }
    }
    float4 b = ((const float4*)bias)[tx];
#pragma unroll
    for (int j = 0; j < 8; ++j) {
        int r = ty * 8 + j;
        if (r < rows) {
            float4 o = make_float4(acc[j][0] + b.x, acc[j][1] + b.y,
                                   acc[j][2] + b.z, acc[j][3] + b.w);
            ((float4*)out)[(size_t)(r0 + r) * 32 + tx] = o;
        }
    }
}

// ---------------- BN statistics (per-column sum / sumsq) ----------------
__global__ __launch_bounds__(256) void k_stats(const float* __restrict__ src, int nRows,
                                               float* __restrict__ st) {
    int c = threadIdx.x & 127;
    int sub = threadIdx.x >> 7;  // 0/1
    int r0 = blockIdx.x * 128;
    int rend = r0 + 128; if (rend > nRows) rend = nRows;
    float s = 0.f, ss = 0.f;
    for (int r = r0 + sub; r < rend; r += 2) {
        float v = src[(size_t)r * 128 + c];
        s += v; ss += v * v;
    }
    atomicAdd(&st[c], s);
    atomicAdd(&st[128 + c], ss);
}

// dst = (doRes ? dst : 0) + maybe_relu(bn(src)); optional bf16 sidecar for next GEMM
__global__ __launch_bounds__(256) void k_bn_apply(float* __restrict__ dst,
                                                  short* __restrict__ dstbf,
                                                  const float* __restrict__ src,
                                                  const float* __restrict__ st,
                                                  const float* __restrict__ g,
                                                  const float* __restrict__ b,
                                                  float invn, int doRelu, int doRes,
                                                  int doBf) {
    int tid = blockIdx.x * blockDim.x + threadIdx.x;
    int cb = (tid & 31) * 4;
    float sc[4], sh[4];
#pragma unroll
    for (int k = 0; k < 4; ++k) {
        float mean = st[cb + k] * invn;
        float var = fmaxf(st[128 + cb + k] * invn - mean * mean, 0.f);
        float s = g[cb + k] * rsqrtf(var + EPSB);
        sc[k] = s; sh[k] = b[cb + k] - mean * s;
    }
    const float4* s4 = (const float4*)src;
    float4* d4 = (float4*)dst;
    const int total = NN * 32;
    for (int i = tid; i < total; i += gridDim.x * blockDim.x) {
        float4 v = s4[i];
        v.x = v.x * sc[0] + sh[0]; v.y = v.y * sc[1] + sh[1];
        v.z = v.z * sc[2] + sh[2]; v.w = v.w * sc[3] + sh[3];
        if (doRelu) {
            v.x = fmaxf(v.x, 0.f); v.y = fmaxf(v.y, 0.f);
            v.z = fmaxf(v.z, 0.f); v.w = fmaxf(v.w, 0.f);
        }
        if (doRes) {
            float4 o = d4[i];
            v.x += o.x; v.y += o.y; v.z += o.z; v.w += o.w;
        }
        d4[i] = v;
        if (doBf) {
            short4 bs;
            bs.x = f2bf(v.x); bs.y = f2bf(v.y); bs.z = f2bf(v.z); bs.w = f2bf(v.w);
            *(short4*)&dstbf[(size_t)i * 4] = bs;
        }
    }
}

// ---------------- GAT score: one thread per (CSR slot, head), float4 loads ----------
__global__ __launch_bounds__(256) void k_gat_score(const __half* __restrict__ xl,
                                                   const __half* __restrict__ xr,
                                                   const float* __restrict__ att,
                                                   const int2* __restrict__ edg,
                                                   float* __restrict__ sc) {
    __shared__ float attS[128];
    if (threadIdx.x < 128) attS[threadIdx.x] = att[threadIdx.x];
    __syncthreads();
    int idx = blockIdx.x * 256 + threadIdx.x;
    int slot = idx >> 2, head = idx & 3;
    if (slot >= NE + NN) return;
    int s, d;
    if (slot < NE) { int2 ed = edg[slot]; s = ed.x; d = ed.y; }
    else { s = slot - NE; d = s; }
    const float4* xlp = (const float4*)(xl + (size_t)s * 128 + head * 32);
    const float4* xrp = (const float4*)(xr + (size_t)d * 128 + head * 32);
    const float* aB = &attS[head * 32];
    float acc = 0.f;
#pragma unroll
    for (int q = 0; q < 4; ++q) {
        float4 A = xlp[q], B = xrp[q];
        const __half2* ah = (const __half2*)&A;
        const __half2* bh = (const __half2*)&B;
#pragma unroll
        for (int j = 0; j < 4; ++j) {
            float2 a2 = __half22float2(ah[j]);
            float2 b2 = __half22float2(bh[j]);
            float ex = a2.x + b2.x, ey = a2.y + b2.y;
            ex = fmaxf(ex, 0.f) + LSLOPE * fminf(ex, 0.f);
            ey = fmaxf(ey, 0.f) + LSLOPE * fminf(ey, 0.f);
            acc += ex * aB[q * 8 + 2 * j] + ey * aB[q * 8 + 2 * j + 1];
        }
    }
    sc[idx] = __expf(acc);  // scores bounded; shift-free exp is exact math
}

// ---------------- Transformer score ----------------
__global__ __launch_bounds__(256) void k_trans_score(const __half* __restrict__ qh,
                                                     const __half* __restrict__ kh,
                                                     const int2* __restrict__ edg,
                                                     float* __restrict__ sc) {
    int idx = blockIdx.x * 256 + threadIdx.x;
    int slot = idx >> 2, head = idx & 3;
    if (slot >= NE) return;
    int2 ed = edg[slot];
    int s = ed.x, d = ed.y;
    const float4* qp = (const float4*)(qh + (size_t)d * 128 + head * 32);
    const float4* kp = (const float4*)(kh + (size_t)s * 128 + head * 32);
    float acc = 0.f;
#pragma unroll
    for (int q = 0; q < 4; ++q) {
        float4 A = qp[q], B = kp[q];
        const __half2* ah = (const __half2*)&A;
        const __half2* bh = (const __half2*)&B;
#pragma unroll
        for (int j = 0; j < 4; ++j) {
            float2 a2 = __half22float2(ah[j]);
            float2 b2 = __half22float2(bh[j]);
            acc += a2.x * b2.x + a2.y * b2.y;
        }
    }
    sc[idx] = __expf(acc * INV_SQRT_C);
}

// ---------------- aggregates: wave/node, half-wave per edge (8 B/lane) --------------
template <int SELF>
__device__ __forceinline__ void aggr_body(int j, int T, int s0, int node, int head,
                                          int c4, const int2* __restrict__ edg,
                                          const float* __restrict__ sc,
                                          const __half* __restrict__ feat,
                                          float& a0, float& a1, float& a2, float& a3,
                                          float& l) {
    bool self = SELF && (j == T - 1);
    int slot = s0 + j;
    int src = self ? node : edg[slot].x;
    size_t scIdx = self ? ((size_t)(NE + node) * 4 + head) : ((size_t)slot * 4 + head);
    float w = sc[scIdx];
    float2 raw = *(const float2*)&feat[(size_t)src * 128 + c4];
    float2 f0 = __half22float2(*(const __half2*)&raw.x);
    float2 f1 = __half22float2(*(const __half2*)&raw.y);
    a0 += w * f0.x; a1 += w * f0.y; a2 += w * f1.x; a3 += w * f1.y; l += w;
}

__global__ __launch_bounds__(256) void k_gat_aggr(const __half* __restrict__ xl,
                                                  const float* __restrict__ sc,
                                                  const float* __restrict__ gbias_l,
                                                  const int* __restrict__ rp,
                                                  const int2* __restrict__ edg,
                                                  float* __restrict__ out) {
    int lane = threadIdx.x & 63;
    int node = blockIdx.x * 4 + (threadIdx.x >> 6);
    if (node >= NN) return;
    int half = lane >> 5;
    int l32 = lane & 31;
    int c4 = l32 * 4;
    int head = l32 >> 3;
    int s0 = rp[node];
    int T = rp[node + 1] - s0 + 1;  // +1: self loop is logical edge T-1
    float a0 = 0.f, a1 = 0.f, a2 = 0.f, a3 = 0.f, l = 0.f;
    int j = half;
    for (; j + 6 < T; j += 8) {
        aggr_body<1>(j, T, s0, node, head, c4, edg, sc, xl, a0, a1, a2, a3, l);
        aggr_body<1>(j + 2, T, s0, node, head, c4, edg, sc, xl, a0, a1, a2, a3, l);
        aggr_body<1>(j + 4, T, s0, node, head, c4, edg, sc, xl, a0, a1, a2, a3, l);
        aggr_body<1>(j + 6, T, s0, node, head, c4, edg, sc, xl, a0, a1, a2, a3, l);
    }
    for (; j < T; j += 2)
        aggr_body<1>(j, T, s0, node, head, c4, edg, sc, xl, a0, a1, a2, a3, l);
    a0 += __shfl_xor(a0, 32); a1 += __shfl_xor(a1, 32);
    a2 += __shfl_xor(a2, 32); a3 += __shfl_xor(a3, 32);
    l += __shfl_xor(l, 32);
    if (half == 0) {
        float inv = 1.f / (l + 1e-16f);
        float4 gb = *(const float4*)&gbias_l[c4];
        float4 o = make_float4(a0 * inv + gb.x, a1 * inv + gb.y,
                               a2 * inv + gb.z, a3 * inv + gb.w);
        *(float4*)&out[(size_t)node * 128 + c4] = o;
    }
}

__global__ __launch_bounds__(256) void k_trans_aggr(const __half* __restrict__ vv,
                                                    const float* __restrict__ sc,
                                                    const float* __restrict__ sT,
                                                    const int* __restrict__ rp,
                                                    const int2* __restrict__ edg,
                                                    float* __restrict__ out) {
    int lane = threadIdx.x & 63;
    int node = blockIdx.x * 4 + (threadIdx.x >> 6);
    if (node >= NN) return;
    int half = lane >> 5;
    int l32 = lane & 31;
    int c4 = l32 * 4;
    int head = l32 >> 3;
    int s0 = rp[node];
    int T = rp[node + 1] - s0;
    float a0 = 0.f, a1 = 0.f, a2 = 0.f, a3 = 0.f, l = 0.f;
    int j = half;
    for (; j + 6 < T; j += 8) {
        aggr_body<0>(j, T, s0, node, head, c4, edg, sc, vv, a0, a1, a2, a3, l);
        aggr_body<0>(j + 2, T, s0, node, head, c4, edg, sc, vv, a0, a1, a2, a3, l);
        aggr_body<0>(j + 4, T, s0, node, head, c4, edg, sc, vv, a0, a1, a2, a3, l);
        aggr_body<0>(j + 6, T, s0, node, head, c4, edg, sc, vv, a0, a1, a2, a3, l);
    }
    for (; j < T; j += 2)
        aggr_body<0>(j, T, s0, node, head, c4, edg, sc, vv, a0, a1, a2, a3, l);
    a0 += __shfl_xor(a0, 32); a1 += __shfl_xor(a1, 32);
    a2 += __shfl_xor(a2, 32); a3 += __shfl_xor(a3, 32);
    l += __shfl_xor(l, 32);
    if (half == 0) {
        float inv = 1.f / (l + 1e-16f);
        float4 st4 = *(const float4*)&sT[(size_t)node * 128 + c4];
        float4 o = make_float4(a0 * inv + st4.x, a1 * inv + st4.y,
                               a2 * inv + st4.z, a3 * inv + st4.w);
        *(float4*)&out[(size_t)node * 128 + c4] = o;
    }
}

// ---------------- pooling phase 1: node-parallel partials (batch sorted) ------------
__global__ __launch_bounds__(256) void k_pool_part(const float* __restrict__ x,
                                                   const int* __restrict__ batch,
                                                   float* __restrict__ psum,
                                                   unsigned* __restrict__ pmax) {
    __shared__ int bs[64];
    int r0 = blockIdx.x * 64;
    if (threadIdx.x < 64) {
        int r = r0 + threadIdx.x;
        bs[threadIdx.x] = (r < NN) ? batch[r] : -1;
    }
    __syncthreads();
    int c = threadIdx.x & 127;
    int sub = threadIdx.x >> 7;
    int curg = -1;
    float s = 0.f, fmx = -INFINITY;
    for (int i = sub; i < 64; i += 2) {
        int r = r0 + i;
        if (r >= NN) break;
        int g = bs[i];
        if (g != curg) {
            if (curg >= 0) {
                atomicAdd(&psum[curg * 128 + c], s);
                atomicMax(&pmax[curg * 128 + c], fenc(fmx));
            }
            curg = g; s = 0.f; fmx = -INFINITY;
        }
        float v = x[(size_t)r * 128 + c];
        s += v; fmx = fmaxf(fmx, v);
    }
    if (curg >= 0) {
        atomicAdd(&psum[curg * 128 + c], s);
        atomicMax(&pmax[curg * 128 + c], fenc(fmx));
    }
}

// ---------------- pooling phase 2: finalize ----------------
__global__ __launch_bounds__(128) void k_pool_final(const float* __restrict__ psum,
                                                    const unsigned* __restrict__ pmax,
                                                    const int* __restrict__ batch,
                                                    float* __restrict__ h) {
    __shared__ int se[2];
    int g = blockIdx.x;
    if (threadIdx.x == 0) {
        int lo = 0, hi = NN;
        while (lo < hi) { int mid = (lo + hi) >> 1; if (batch[mid] < g) lo = mid + 1; else hi = mid; }
        se[0] = lo;
        hi = NN;
        while (lo < hi) { int mid = (lo + hi) >> 1; if (batch[mid] < g + 1) lo = mid + 1; else hi = mid; }
        se[1] = lo;
    }
    __syncthreads();
    int cnt = se[1] - se[0];
    int c = threadIdx.x;
    float xm = psum[g * 128 + c] / fmaxf((float)cnt, 1.f);
    float xx = (cnt > 0) ? fdec(pmax[g * 128 + c]) : 0.f;
    h[g * 256 + c] = xm;
    h[g * 256 + 128 + c] = xx;
}

// ---------------- head ----------------
__global__ __launch_bounds__(128) void k_head1(const float* __restrict__ h,
                                               const float* __restrict__ W,
                                               const float* __restrict__ b,
                                               float* __restrict__ t1) {
    __shared__ float hr[256];
    int row = blockIdx.x;
    int t = threadIdx.x;
    hr[t] = h[row * 256 + t];
    hr[t + 128] = h[row * 256 + 128 + t];
    __syncthreads();
    float acc = b[t];
#pragma unroll 4
    for (int k = 0; k < 256; ++k) acc += hr[k] * W[k * 128 + t];
    t1[row * 128 + t] = acc;
}

__global__ __launch_bounds__(64) void k_head2(const float* __restrict__ t1,
                                              const float* __restrict__ st,
                                              const float* __restrict__ og,
                                              const float* __restrict__ obe,
                                              const float* __restrict__ W2,
                                              const float* __restrict__ b2,
                                              const float* __restrict__ W3,
                                              const float* __restrict__ b3,
                                              float* __restrict__ out) {
    __shared__ float v[128];
    int row = blockIdx.x, t = threadIdx.x;
    const float invn = 1.f / NG;
#pragma unroll
    for (int half = 0; half < 2; ++half) {
        int ch = t + half * 64;
        float mean = st[ch] * invn;
        float var = fmaxf(st[128 + ch] * invn - mean * mean, 0.f);
        float scv = og[ch] * rsqrtf(var + EPSB);
        float shv = obe[ch] - mean * scv;
        float a = t1[row * 128 + ch] * scv + shv;
        v[ch] = fmaxf(a, 0.f);
    }
    __syncthreads();
    float acc = b2[t];
#pragma unroll 4
    for (int k = 0; k < 128; ++k) acc += v[k] * W2[k * 64 + t];
    float p = fmaxf(acc, 0.f) * W3[t];
    p += __shfl_xor(p, 1); p += __shfl_xor(p, 2); p += __shfl_xor(p, 4);
    p += __shfl_xor(p, 8); p += __shfl_xor(p, 16); p += __shfl_xor(p, 32);
    if (t == 0) out[row] = p + b3[0];
}

// ---------------- launch ----------------
extern "C" void kernel_launch(void* const* d_in, const int* in_sizes, int n_in,
                              void* d_out, int out_size, void* d_ws, size_t ws_size,
                              hipStream_t stream) {
    const float* x_in   = (const float*)d_in[0];
    const int*   ei     = (const int*)d_in[1];
    const int*   batch  = (const int*)d_in[2];
    const float* emb_W  = (const float*)d_in[3];
    const float* emb_b  = (const float*)d_in[4];
    const float* emb_g  = (const float*)d_in[5];
    const float* emb_be = (const float*)d_in[6];
    const float* gWl    = (const float*)d_in[7];
    const float* gWr    = (const float*)d_in[8];
    const float* gbl    = (const float*)d_in[9];
    const float* gbr    = (const float*)d_in[10];
    const float* gatt   = (const float*)d_in[11];
    const float* gbias  = (const float*)d_in[12];
    const float* gg     = (const float*)d_in[13];
    const float* gbe    = (const float*)d_in[14];
    const float* tWq    = (const float*)d_in[15];
    const float* tWk    = (const float*)d_in[16];
    const float* tWv    = (const float*)d_in[17];
    const float* tWs    = (const float*)d_in[18];
    const float* tbq    = (const float*)d_in[19];
    const float* tbk    = (const float*)d_in[20];
    const float* tbv    = (const float*)d_in[21];
    const float* tbs    = (const float*)d_in[22];
    const float* tg     = (const float*)d_in[23];
    const float* tbe    = (const float*)d_in[24];
    const float* oW1    = (const float*)d_in[25];
    const float* ob1    = (const float*)d_in[26];
    const float* og     = (const float*)d_in[27];
    const float* obe    = (const float*)d_in[28];
    const float* oW2    = (const float*)d_in[29];
    const float* ob2    = (const float*)d_in[30];
    const float* oW3    = (const float*)d_in[31];
    const float* ob3    = (const float*)d_in[32];
    float* out = (float*)d_out;

    const size_t NDsz = (size_t)NN * 128;
    float* x     = (float*)d_ws;
    float* bA    = x + NDsz;
    float* bC    = bA + NDsz;
    float* stats = bC + NDsz;        // 7 * 256 floats
    float* hpool = stats + 7 * 256;  // 256*256
    float* t1    = hpool + 65536;    // 256*128
    float* scb   = t1 + 32768;                 // (NE+NN)*4 scores
    __half* xlh  = (__half*)(scb + (size_t)(NE + NN) * 4);  // xl / K
    __half* xrh  = xlh + NDsz;                 // xr / Q
    __half* vh   = xrh + NDsz;                 // V
    short* xbf   = (short*)(vh + NDsz);        // bf16 copy of x (GEMM A input)
    short* Wt    = xbf + NDsz;                 // 12 * 128*128 bf16 transposed
    int* deg     = (int*)(Wt + 12 * 16384);
    int* rp      = deg + NN;
    int* cursor  = rp + NN + 1;
    int2* edg    = (int2*)(cursor + NN);       // NE+64 packed (src,dst)
    int* bsum    = (int*)(edg + NE + 64);
    int* boff    = bsum + 256;
    float* psum  = (float*)(boff + 256);            // NG*128
    unsigned* pmax = (unsigned*)(psum + NG * 128);  // NG*128

    hipMemsetAsync(deg, 0, NN * sizeof(int), stream);
    hipMemsetAsync(stats, 0, 7 * 256 * sizeof(float), stream);
    hipMemsetAsync(psum, 0, NG * 128 * 2 * sizeof(float), stream);  // psum + pmax

    // weight prep (bf16 transposed)
    k_prep<<<12, 256, 0, stream>>>(gWl, gWr, tWq, tWk, tWv, tWs, Wt);

    // CSR by destination (parallel 3-phase scan)
    k_deg<<<(NE + 255) / 256, 256, 0, stream>>>(ei, deg);
    k_scan1<<<NB, 256, 0, stream>>>(deg, bsum);
    k_scan2<<<1, 256, 0, stream>>>(bsum, boff, rp);
    k_scan3<<<NB, 256, 0, stream>>>(deg, boff, rp, cursor);
    k_fill<<<(NE + 255) / 256, 256, 0, stream>>>(ei, cursor, edg);

    const int gEmb  = (NN + 63) / 64;
    const int gGemm = (NN + 127) / 128;
    const int gStat = (NN + 127) / 128;
    const int gNode = (NN + 3) / 4;
    const int gScG  = ((NE + NN) * 4 + 255) / 256;
    const int gScT  = (NE * 4 + 255) / 256;
    const int gPool = (NN + 63) / 64;

    // embedding + BN + relu
    k_gemm_emb<<<gEmb, 256, 0, stream>>>(x_in, emb_W, emb_b, bA, NN);
    k_stats<<<gStat, 256, 0, stream>>>(bA, NN, stats);
    k_bn_apply<<<1024, 256, 0, stream>>>(x, xbf, bA, stats, emb_g, emb_be, 1.f / NN, 1, 0, 1);

    // 4 GATv2 layers
    for (int l = 0; l < NL; ++l) {
        k_gemm2<1, 1><<<gGemm, 256, 0, stream>>>(xbf, Wt + (size_t)l * 16384,
                                                 Wt + (size_t)(4 + l) * 16384,
                                                 gbl + l * 128, gbr + l * 128, xlh, xrh, NN);
        k_gat_score<<<gScG, 256, 0, stream>>>(xlh, xrh, gatt + l * 128, edg, scb);
        k_gat_aggr<<<gNode, 256, 0, stream>>>(xlh, scb, gbias + l * 128, rp, edg, bC);
        k_stats<<<gStat, 256, 0, stream>>>(bC, NN, stats + (1 + l) * 256);
        k_bn_apply<<<1024, 256, 0, stream>>>(x, xbf, bC, stats + (1 + l) * 256, gg + l * 128,
                                             gbe + l * 128, 1.f / NN, 1, 1, 1);
    }

    // TransformerConv
    k_gemm2<1, 1><<<gGemm, 256, 0, stream>>>(xbf, Wt + (size_t)8 * 16384,
                                             Wt + (size_t)9 * 16384, tbq, tbk, xrh, xlh, NN);  // Q, K
    k_gemm2<1, 0><<<gGemm, 256, 0, stream>>>(xbf, Wt + (size_t)10 * 16384,
                                             Wt + (size_t)11 * 16384, tbv, tbs, vh, bA, NN);   // V, skip
    k_trans_score<<<gScT, 256, 0, stream>>>(xrh, xlh, edg, scb);
    k_trans_aggr<<<gNode, 256, 0, stream>>>(vh, scb, bA, rp, edg, bC);
    k_stats<<<gStat, 256, 0, stream>>>(bC, NN, stats + 5 * 256);
    k_bn_apply<<<1024, 256, 0, stream>>>(x, xbf, bC, stats + 5 * 256, tg, tbe, 1.f / NN, 0, 1, 0);

    // pooling + head
    k_pool_part<<<gPool, 256, 0, stream>>>(x, batch, psum, pmax);
    k_pool_final<<<NG, 128, 0, stream>>>(psum, pmax, batch, hpool);
    k_head1<<<NG, 128, 0, stream>>>(hpool, oW1, ob1, t1);
    k_stats<<<(NG + 127) / 128, 256, 0, stream>>>(t1, NG, stats + 6 * 256);
    k_head2<<<NG, 64, 0, stream>>>(t1, stats + 6 * 256, og, obe, oW2, ob2, oW3, ob3, out);
}